// Round 9
// baseline (750.402 us; speedup 1.0000x reference)
//
#include <hip/hip_runtime.h>
#include <cstdint>

// ---------- helpers ----------
typedef __attribute__((ext_vector_type(8))) short short8;   // 8 x bf16 (4 VGPRs)
typedef __attribute__((ext_vector_type(4))) float f32x4;

__device__ __forceinline__ float b2f(unsigned short u) {
    return __uint_as_float(((unsigned int)u) << 16);
}
__device__ __forceinline__ unsigned short f2b(float f) {   // RNE f32->bf16
    unsigned int u = __float_as_uint(f);
    u += 0x7FFFu + ((u >> 16) & 1u);
    return (unsigned short)(u >> 16);
}

// ---------- transpose + fp32->bf16 convert: w[K][N] -> wT[N][K] ----------
__global__ __launch_bounds__(256) void k_transpose_bf16(
        const float* __restrict__ w, unsigned short* __restrict__ wT, int K, int N) {
    __shared__ float tile[32][33];
    int n0 = blockIdx.x * 32, k0 = blockIdx.y * 32;
    int tx = threadIdx.x, ty = threadIdx.y;   // block (32,8)
#pragma unroll
    for (int i = 0; i < 4; i++)
        tile[ty + 8 * i][tx] = w[(size_t)(k0 + ty + 8 * i) * N + n0 + tx];
    __syncthreads();
#pragma unroll
    for (int i = 0; i < 4; i++)
        wT[(size_t)(n0 + ty + 8 * i) * K + k0 + tx] = f2b(tile[tx][ty + 8 * i]);
}

// ---------- layernorm (fp32 in, bf16 out), one row (C=1024) per block ----------
__global__ __launch_bounds__(256) void k_layernorm(
        const float* __restrict__ x, const float* __restrict__ w,
        unsigned short* __restrict__ out) {
    int row = blockIdx.x, tid = threadIdx.x;
    const float4* xr = (const float4*)(x + (size_t)row * 1024);
    float4 v = xr[tid];
    float s  = v.x + v.y + v.z + v.w;
    float ss = v.x * v.x + v.y * v.y + v.z * v.z + v.w * v.w;
#pragma unroll
    for (int off = 32; off >= 1; off >>= 1) {
        s  += __shfl_down(s, off);
        ss += __shfl_down(ss, off);
    }
    __shared__ float red[10];
    if ((tid & 63) == 0) { red[tid >> 6] = s; red[4 + (tid >> 6)] = ss; }
    __syncthreads();
    if (tid == 0) {
        float S  = red[0] + red[1] + red[2] + red[3];
        float SS = red[4] + red[5] + red[6] + red[7];
        float mu  = S * (1.0f / 1024.0f);
        float var = SS * (1.0f / 1024.0f) - mu * mu;
        red[8] = mu; red[9] = rsqrtf(var + 1e-5f);
    }
    __syncthreads();
    float mu = red[8], rs = red[9];
    float4 wv = ((const float4*)w)[tid];
    ushort4 pk;
    pk.x = f2b((v.x - mu) * rs * wv.x);
    pk.y = f2b((v.y - mu) * rs * wv.y);
    pk.z = f2b((v.z - mu) * rs * wv.z);
    pk.w = f2b((v.w - mu) * rs * wv.w);
    *(ushort4*)(out + (size_t)row * 1024 + tid * 4) = pk;
}

// ---------- bf16 MFMA GEMM: C[M][N] = A[M][K] @ BT[N][K]^T (+ epilogue) ----------
// BK=64, column-rotate LDS swizzle, VGPR register-prefetch pipeline (R8 pattern):
// next slab's global loads issue after the staging barrier and overlap this
// slab's MFMA compute; regs -> LDS next iteration.
// EPI: 1 = store bf16, 2 = RES + acc -> f32, 3 = gelu(acc) -> bf16
// TN: 128 (4 waves 64x64) or 64 (4 waves 32x64)
template <int EPI, int TN>
__global__ __launch_bounds__(256) void k_gemm_bt(
        const unsigned short* __restrict__ A, const unsigned short* __restrict__ BT,
        const float* __restrict__ RES, void* __restrict__ OUT,
        int M, int N, int K) {
    constexpr int MI = (TN == 128) ? 4 : 2;        // m-subtiles per wave
    constexpr int NB = TN / 32;                    // B uint4-chunks per thread
    __shared__ __align__(16) unsigned short As[128 * 64];
    __shared__ __align__(16) unsigned short Bs[TN * 64];
    int tid  = threadIdx.x;
    int lane = tid & 63, wave = tid >> 6;
    int quad = lane >> 4, qr = lane & 15;
    int wm_off = (TN == 128) ? (wave >> 1) * 64 : wave * 32;
    int wn_off = (TN == 128) ? (wave & 1) * 64 : 0;
    int m0 = blockIdx.y * 128, n0 = blockIdx.x * TN;
    // swizzle: logical col c of row r lives at lds col (c + 8*(r&7)) & 63
    // staging (uint4 units): chunk id = t*256 + tid; row = id>>3, colchunk = id&7
    int arow[4], acol[4];
#pragma unroll
    for (int t = 0; t < 4; t++) {
        int id = t * 256 + tid;
        arow[t] = id >> 3;
        acol[t] = (id & 7) * 8;
    }
    int cswz[2];
#pragma unroll
    for (int kk = 0; kk < 2; kk++) cswz[kk] = 8 * (((kk * 4) + quad + (qr & 7)) & 7);

    uint4 pa[4], pb[NB];
    {   // prologue: prefetch k0 = 0 slabs
#pragma unroll
        for (int t = 0; t < 4; t++)
            pa[t] = *(const uint4*)&A[(size_t)(m0 + arow[t]) * K + acol[t]];
#pragma unroll
        for (int t = 0; t < NB; t++)
            pb[t] = *(const uint4*)&BT[(size_t)(n0 + arow[t]) * K + acol[t]];
    }
    f32x4 acc[MI][4] = {};
    for (int k0 = 0; k0 < K; k0 += 64) {
        __syncthreads();   // prev compute's LDS reads done
#pragma unroll
        for (int t = 0; t < 4; t++)
            *(uint4*)&As[arow[t] * 64 + ((acol[t] + 8 * (arow[t] & 7)) & 63)] = pa[t];
#pragma unroll
        for (int t = 0; t < NB; t++)
            *(uint4*)&Bs[arow[t] * 64 + ((acol[t] + 8 * (arow[t] & 7)) & 63)] = pb[t];
        __syncthreads();
        if (k0 + 64 < K) {   // prefetch next slab; overlaps MFMA below
#pragma unroll
            for (int t = 0; t < 4; t++)
                pa[t] = *(const uint4*)&A[(size_t)(m0 + arow[t]) * K + k0 + 64 + acol[t]];
#pragma unroll
            for (int t = 0; t < NB; t++)
                pb[t] = *(const uint4*)&BT[(size_t)(n0 + arow[t]) * K + k0 + 64 + acol[t]];
        }
#pragma unroll
        for (int kk = 0; kk < 2; kk++) {
            short8 af[MI], bfr[4];
#pragma unroll
            for (int i = 0; i < MI; i++) af[i]  = *(const short8*)&As[(wm_off + i * 16 + qr) * 64 + cswz[kk]];
#pragma unroll
            for (int j = 0; j < 4; j++)  bfr[j] = *(const short8*)&Bs[(wn_off + j * 16 + qr) * 64 + cswz[kk]];
#pragma unroll
            for (int i = 0; i < MI; i++)
#pragma unroll
                for (int j = 0; j < 4; j++)
                    acc[i][j] = __builtin_amdgcn_mfma_f32_16x16x32_bf16(af[i], bfr[j], acc[i][j], 0, 0, 0);
        }
    }
    // epilogue: C/D layout col=lane&15, row=quad*4+reg
#pragma unroll
    for (int i = 0; i < MI; i++) {
#pragma unroll
        for (int j = 0; j < 4; j++) {
#pragma unroll
            for (int r = 0; r < 4; r++) {
                int row = m0 + wm_off + i * 16 + quad * 4 + r;
                int col = n0 + wn_off + j * 16 + qr;
                size_t idx = (size_t)row * N + col;
                float v = acc[i][j][r];
                if (EPI == 1)      ((unsigned short*)OUT)[idx] = f2b(v);
                else if (EPI == 2) ((float*)OUT)[idx] = RES[idx] + v;
                else {
                    // tanh-form GELU via exp2: g = v*t/(t+1), t = 2^(2u/ln2)
                    float u = v * fmaf(v * v, 0.035677408f, 0.79788456f);
                    float e = fminf(u * 2.885390082f, 80.0f);   // guard inf/inf
                    float t = exp2f(e);
                    float g = v * t / (t + 1.0f);
                    ((unsigned short*)OUT)[idx] = f2b(g);
                }
            }
        }
    }
}

// ---------- MFMA causal flash attention, K-chunk=128, static-max softmax ------
// Register-prefetch pipeline: chunk j+2's global loads issue after the staging
// barrier and overlap chunk j's compute; regs -> LDS next iteration.
// qkv bf16 [4096][3072] (q|k|v blocks of 1024 cols), out bf16 [4096][1024]
__global__ __launch_bounds__(256) void k_attn(
        const unsigned short* __restrict__ qkv, unsigned short* __restrict__ out) {
    __shared__ unsigned short Ks[128][72];      // K rows (Q staged here first)
    __shared__ unsigned short Vt[64][136];      // [dim][key 0..127]
    __shared__ unsigned short Ps[4][16][136];   // per wave [q][key 0..127] (wave-private)

    const float C1 = 0.18033688f;   // 0.125 * log2(e)
    const float C2 = 5.77078016f;   // 4.0   * log2(e)  (static max m=4)

    int l = blockIdx.x;                // 0..1023; big qb dispatched first
    int h = l & 15;
    int qb = 63 - (l >> 4);
    int q0 = qb * 64;

    int tid = threadIdx.x;
    int wave = tid >> 6, lane = tid & 63;
    int lane16 = lane & 15, quad = lane >> 4;

    // ---- stage Q through Ks rows 0..63, read loop-invariant A-frags ----
    {
        int srow = tid >> 2, sc0 = (tid & 3) * 16;
        size_t base = (size_t)(q0 + srow) * 3072 + h * 64 + sc0;
        *(uint4*)&Ks[srow][sc0]     = *(const uint4*)&qkv[base];
        *(uint4*)&Ks[srow][sc0 + 8] = *(const uint4*)&qkv[base + 8];
    }
    __syncthreads();
    short8 aq0 = *(const short8*)&Ks[wave * 16 + lane16][quad * 8];
    short8 aq1 = *(const short8*)&Ks[wave * 16 + lane16][32 + quad * 8];

    f32x4 Oacc[4] = {};                // lane holds O[q=quad*4+r][d=dt*16+lane16]
    float l_part[4] = {0.f, 0.f, 0.f, 0.f};

    int srow = tid >> 1, sc0 = (tid & 1) * 32;   // K staging coords
    int vk = (lane & 31) * 2;                    // V staging: even local key
    int d0 = wave * 16 + (lane >> 5) * 8;

    // prefetch registers (chunk kc): K 4x uint4, V 4x uint4
    uint4 pk0, pk1, pk2, pk3, pv0, pv1, pv2, pv3;
    {   // prefetch chunk 0
        size_t base = (size_t)srow * 3072 + 1024 + h * 64 + sc0;
        pk0 = *(const uint4*)&qkv[base];
        pk1 = *(const uint4*)&qkv[base + 8];
        pk2 = *(const uint4*)&qkv[base + 16];
        pk3 = *(const uint4*)&qkv[base + 24];
        size_t vb0 = (size_t)vk * 3072 + 2048 + h * 64 + d0;
        pv0 = *(const uint4*)&qkv[vb0];
        pv1 = *(const uint4*)&qkv[vb0 + 3072];
        size_t vb1 = (size_t)(64 + vk) * 3072 + 2048 + h * 64 + d0;
        pv2 = *(const uint4*)&qkv[vb1];
        pv3 = *(const uint4*)&qkv[vb1 + 3072];
    }

    for (int kc = 0; kc <= qb; kc += 2) {      // 128 keys per iteration
        __syncthreads();   // prev-iter LDS reads done (covers Q-frag reads at kc=0)
        {   // write prefetched K chunk to LDS
            *(uint4*)&Ks[srow][sc0]      = pk0;
            *(uint4*)&Ks[srow][sc0 + 8]  = pk1;
            *(uint4*)&Ks[srow][sc0 + 16] = pk2;
            *(uint4*)&Ks[srow][sc0 + 24] = pk3;
        }
        {   // write prefetched V chunk TRANSPOSED, key-pairs packed as b32
            const unsigned short* pe0 = (const unsigned short*)&pv0;
            const unsigned short* po0 = (const unsigned short*)&pv1;
            const unsigned short* pe1 = (const unsigned short*)&pv2;
            const unsigned short* po1 = (const unsigned short*)&pv3;
#pragma unroll
            for (int j = 0; j < 8; j++) {
                *(uint32_t*)&Vt[d0 + j][vk]      = (uint32_t)pe0[j] | ((uint32_t)po0[j] << 16);
                *(uint32_t*)&Vt[d0 + j][64 + vk] = (uint32_t)pe1[j] | ((uint32_t)po1[j] << 16);
            }
        }
        __syncthreads();

        if (kc + 2 <= qb) {   // issue next chunk's loads; overlap with compute below
            size_t base = (size_t)((kc + 2) * 64 + srow) * 3072 + 1024 + h * 64 + sc0;
            pk0 = *(const uint4*)&qkv[base];
            pk1 = *(const uint4*)&qkv[base + 8];
            pk2 = *(const uint4*)&qkv[base + 16];
            pk3 = *(const uint4*)&qkv[base + 24];
            size_t vb0 = (size_t)((kc + 2) * 64 + vk) * 3072 + 2048 + h * 64 + d0;
            pv0 = *(const uint4*)&qkv[vb0];
            pv1 = *(const uint4*)&qkv[vb0 + 3072];
            size_t vb1 = (size_t)((kc + 3) * 64 + vk) * 3072 + 2048 + h * 64 + d0;
            pv2 = *(const uint4*)&qkv[vb1];
            pv3 = *(const uint4*)&qkv[vb1 + 3072];
        }

        // ---- S = Q K^T  (16q x 128k per wave) ----
        f32x4 sacc[8] = {};
#pragma unroll
        for (int kt = 0; kt < 8; kt++) {
            short8 bk0 = *(const short8*)&Ks[kt * 16 + lane16][quad * 8];
            short8 bk1 = *(const short8*)&Ks[kt * 16 + lane16][32 + quad * 8];
            sacc[kt] = __builtin_amdgcn_mfma_f32_16x16x32_bf16(aq0, bk0, sacc[kt], 0, 0, 0);
            sacc[kt] = __builtin_amdgcn_mfma_f32_16x16x32_bf16(aq1, bk1, sacc[kt], 0, 0, 0);
        }

        // ---- static-max softmax: p = 2^(s*C1 - C2); mask only on last chunk ----
        bool domask = (kc + 2 > qb);   // wave-uniform
#pragma unroll
        for (int r = 0; r < 4; r++) {
            int qrow = q0 + wave * 16 + quad * 4 + r;
#pragma unroll
            for (int kt = 0; kt < 8; kt++) {
                float s = sacc[kt][r];
                if (domask) {
                    int key = kc * 64 + kt * 16 + lane16;
                    s = (key <= qrow) ? s : -__builtin_inff();
                }
                float p = exp2f(fmaf(s, C1, -C2));   // masked -> 0
                l_part[r] += p;
                Ps[wave][quad * 4 + r][kt * 16 + lane16] = f2b(p);
            }
        }
        // no barrier: Ps is wave-private; in-wave RAW ordered by lgkmcnt

        // ---- O += P V  (A=P rows, B=V^T rows, both key-contiguous) ----
#pragma unroll
        for (int s = 0; s < 4; s++) {
            short8 ap = *(const short8*)&Ps[wave][lane16][s * 32 + quad * 8];
#pragma unroll
            for (int dt = 0; dt < 4; dt++) {
                short8 bv = *(const short8*)&Vt[dt * 16 + lane16][s * 32 + quad * 8];
                Oacc[dt] = __builtin_amdgcn_mfma_f32_16x16x32_bf16(ap, bv, Oacc[dt], 0, 0, 0);
            }
        }
    }

    // deferred l reduction (sum over lane16 key-group) + output
    float invl[4];
#pragma unroll
    for (int r = 0; r < 4; r++) {
        float lf = l_part[r];
        lf += __shfl_xor(lf, 1);
        lf += __shfl_xor(lf, 2);
        lf += __shfl_xor(lf, 4);
        lf += __shfl_xor(lf, 8);
        invl[r] = 1.0f / lf;
    }
#pragma unroll
    for (int dt = 0; dt < 4; dt++) {
#pragma unroll
        for (int r = 0; r < 4; r++) {
            int qrow = q0 + wave * 16 + quad * 4 + r;
            out[(size_t)qrow * 1024 + h * 64 + dt * 16 + lane16] = f2b(Oacc[dt][r] * invl[r]);
        }
    }
}

// ---------- launch ----------
extern "C" void kernel_launch(void* const* d_in, const int* in_sizes, int n_in,
                              void* d_out, int out_size, void* d_ws, size_t ws_size,
                              hipStream_t stream) {
    const float* x      = (const float*)d_in[0];
    const float* w_qkv  = (const float*)d_in[1];
    const float* w_attn = (const float*)d_in[2];
    const float* w_fc   = (const float*)d_in[3];
    const float* w_mlp  = (const float*)d_in[4];
    const float* ln1w   = (const float*)d_in[5];
    const float* ln2w   = (const float*)d_in[6];

    char* ws = (char*)d_ws;   // total 112 MB, no aliasing
    unsigned short* h      = (unsigned short*)(ws + 0);          //  8 MB
    unsigned short* wqkvT  = (unsigned short*)(ws + 8388608);    //  6 MB
    unsigned short* wattnT = (unsigned short*)(ws + 14680064);   //  2 MB
    unsigned short* wfcT   = (unsigned short*)(ws + 16777216);   //  8 MB
    unsigned short* wmlpT  = (unsigned short*)(ws + 25165824);   //  8 MB
    unsigned short* qkv    = (unsigned short*)(ws + 33554432);   // 24 MB
    unsigned short* attno  = (unsigned short*)(ws + 58720256);   //  8 MB
    float*          x2     = (float*)(ws + 67108864);            // 16 MB
    unsigned short* fcact  = (unsigned short*)(ws + 83886080);   // 32 MB
    float* outF = (float*)d_out;

    dim3 tb(32, 8);
    k_transpose_bf16<<<dim3(96, 32),  tb, 0, stream>>>(w_qkv,  wqkvT,  1024, 3072);
    k_transpose_bf16<<<dim3(32, 32),  tb, 0, stream>>>(w_attn, wattnT, 1024, 1024);
    k_transpose_bf16<<<dim3(128, 32), tb, 0, stream>>>(w_fc,   wfcT,   1024, 4096);
    k_transpose_bf16<<<dim3(32, 128), tb, 0, stream>>>(w_mlp,  wmlpT,  4096, 1024);

    k_layernorm<<<4096, 256, 0, stream>>>(x, ln1w, h);
    k_gemm_bt<1, 128><<<dim3(24, 32), 256, 0, stream>>>(h, wqkvT, nullptr, qkv, 4096, 3072, 1024);
    k_attn<<<1024, 256, 0, stream>>>(qkv, attno);
    k_gemm_bt<2, 64><<<dim3(16, 32), 256, 0, stream>>>(attno, wattnT, x, x2, 4096, 1024, 1024);
    k_layernorm<<<4096, 256, 0, stream>>>(x2, ln2w, h);
    k_gemm_bt<3, 128><<<dim3(32, 32), 256, 0, stream>>>(h, wfcT, nullptr, fcact, 4096, 4096, 1024);
    k_gemm_bt<2, 64><<<dim3(16, 32), 256, 0, stream>>>(fcact, wmlpT, x2, outF, 4096, 1024, 4096);
}

// Round 10
// 371.560 us; speedup vs baseline: 2.0196x; 2.0196x over previous
//
#include <hip/hip_runtime.h>
#include <cstdint>

// ---------- helpers ----------
typedef __attribute__((ext_vector_type(8))) short short8;   // 8 x bf16 (4 VGPRs)
typedef __attribute__((ext_vector_type(4))) float f32x4;

__device__ __forceinline__ float b2f(unsigned short u) {
    return __uint_as_float(((unsigned int)u) << 16);
}
__device__ __forceinline__ unsigned short f2b(float f) {   // RNE f32->bf16
    unsigned int u = __float_as_uint(f);
    u += 0x7FFFu + ((u >> 16) & 1u);
    return (unsigned short)(u >> 16);
}

// ---------- transpose + fp32->bf16 convert: w[K][N] -> wT[N][K] ----------
__global__ __launch_bounds__(256) void k_transpose_bf16(
        const float* __restrict__ w, unsigned short* __restrict__ wT, int K, int N) {
    __shared__ float tile[32][33];
    int n0 = blockIdx.x * 32, k0 = blockIdx.y * 32;
    int tx = threadIdx.x, ty = threadIdx.y;   // block (32,8)
#pragma unroll
    for (int i = 0; i < 4; i++)
        tile[ty + 8 * i][tx] = w[(size_t)(k0 + ty + 8 * i) * N + n0 + tx];
    __syncthreads();
#pragma unroll
    for (int i = 0; i < 4; i++)
        wT[(size_t)(n0 + ty + 8 * i) * K + k0 + tx] = f2b(tile[tx][ty + 8 * i]);
}

// ---------- layernorm (fp32 in, bf16 out), one row (C=1024) per block ----------
__global__ __launch_bounds__(256) void k_layernorm(
        const float* __restrict__ x, const float* __restrict__ w,
        unsigned short* __restrict__ out) {
    int row = blockIdx.x, tid = threadIdx.x;
    const float4* xr = (const float4*)(x + (size_t)row * 1024);
    float4 v = xr[tid];
    float s  = v.x + v.y + v.z + v.w;
    float ss = v.x * v.x + v.y * v.y + v.z * v.z + v.w * v.w;
#pragma unroll
    for (int off = 32; off >= 1; off >>= 1) {
        s  += __shfl_down(s, off);
        ss += __shfl_down(ss, off);
    }
    __shared__ float red[10];
    if ((tid & 63) == 0) { red[tid >> 6] = s; red[4 + (tid >> 6)] = ss; }
    __syncthreads();
    if (tid == 0) {
        float S  = red[0] + red[1] + red[2] + red[3];
        float SS = red[4] + red[5] + red[6] + red[7];
        float mu  = S * (1.0f / 1024.0f);
        float var = SS * (1.0f / 1024.0f) - mu * mu;
        red[8] = mu; red[9] = rsqrtf(var + 1e-5f);
    }
    __syncthreads();
    float mu = red[8], rs = red[9];
    float4 wv = ((const float4*)w)[tid];
    ushort4 pk;
    pk.x = f2b((v.x - mu) * rs * wv.x);
    pk.y = f2b((v.y - mu) * rs * wv.y);
    pk.z = f2b((v.z - mu) * rs * wv.z);
    pk.w = f2b((v.w - mu) * rs * wv.w);
    *(ushort4*)(out + (size_t)row * 1024 + tid * 4) = pk;
}

// ---------- bf16 MFMA GEMM: C[M][N] = A[M][K] @ BT[N][K]^T (+ epilogue) ----------
// BK=64, column-rotate LDS swizzle (conflict-free: R9 measured 0 conflicts),
// VGPR register-prefetch pipeline with NAMED uint4 scalars (R9's arrays spilled
// to scratch: 413 MB WRITE_SIZE; attn's named-var pattern does not spill).
// __launch_bounds__(256,2): explicit 256-VGPR budget so allocator never spills.
// EPI: 1 = store bf16, 2 = RES + acc -> f32, 3 = gelu(acc) -> bf16
// TN: 128 (4 waves 64x64) or 64 (4 waves 32x64)
template <int EPI, int TN>
__global__ __launch_bounds__(256, 2) void k_gemm_bt(
        const unsigned short* __restrict__ A, const unsigned short* __restrict__ BT,
        const float* __restrict__ RES, void* __restrict__ OUT,
        int M, int N, int K) {
    constexpr int MI = (TN == 128) ? 4 : 2;        // m-subtiles per wave
    __shared__ __align__(16) unsigned short As[128 * 64];
    __shared__ __align__(16) unsigned short Bs[TN * 64];
    int tid  = threadIdx.x;
    int lane = tid & 63, wave = tid >> 6;
    int quad = lane >> 4, qr = lane & 15;
    int wm_off = (TN == 128) ? (wave >> 1) * 64 : wave * 32;
    int wn_off = (TN == 128) ? (wave & 1) * 64 : 0;
    int m0 = blockIdx.y * 128, n0 = blockIdx.x * TN;
    // staging decomposition: chunk t covers row t*32 + r0, logical col c0;
    // swizzle (c + 8*(r&7)) & 63 -> chunk-invariant LDS col cs
    int r0 = tid >> 3;                      // 0..31
    int c0 = (tid & 7) * 8;
    int cs = 8 * (((tid & 7) + (r0 & 7)) & 7);
    int cswz[2];
#pragma unroll
    for (int kk = 0; kk < 2; kk++) cswz[kk] = 8 * (((kk * 4) + quad + (qr & 7)) & 7);

    const unsigned short* Ap = A  + (size_t)(m0 + r0) * K + c0;
    const unsigned short* Bp = BT + (size_t)(n0 + r0) * K + c0;
    const size_t sA = (size_t)32 * K;

    uint4 pa0, pa1, pa2, pa3, pb0, pb1, pb2, pb3;
    pa0 = *(const uint4*)(Ap);
    pa1 = *(const uint4*)(Ap + sA);
    pa2 = *(const uint4*)(Ap + 2 * sA);
    pa3 = *(const uint4*)(Ap + 3 * sA);
    pb0 = *(const uint4*)(Bp);
    pb1 = *(const uint4*)(Bp + sA);
    if constexpr (TN == 128) {
        pb2 = *(const uint4*)(Bp + 2 * sA);
        pb3 = *(const uint4*)(Bp + 3 * sA);
    }

    f32x4 acc[MI][4] = {};
    for (int k0 = 0; k0 < K; k0 += 64) {
        __syncthreads();   // prev compute's LDS reads done
        *(uint4*)&As[(r0)      * 64 + cs] = pa0;
        *(uint4*)&As[(32 + r0) * 64 + cs] = pa1;
        *(uint4*)&As[(64 + r0) * 64 + cs] = pa2;
        *(uint4*)&As[(96 + r0) * 64 + cs] = pa3;
        *(uint4*)&Bs[(r0)      * 64 + cs] = pb0;
        *(uint4*)&Bs[(32 + r0) * 64 + cs] = pb1;
        if constexpr (TN == 128) {
            *(uint4*)&Bs[(64 + r0) * 64 + cs] = pb2;
            *(uint4*)&Bs[(96 + r0) * 64 + cs] = pb3;
        }
        __syncthreads();
        if (k0 + 64 < K) {   // prefetch next slab; vmcnt waits land next iteration
            int k = k0 + 64;
            pa0 = *(const uint4*)(Ap + k);
            pa1 = *(const uint4*)(Ap + sA + k);
            pa2 = *(const uint4*)(Ap + 2 * sA + k);
            pa3 = *(const uint4*)(Ap + 3 * sA + k);
            pb0 = *(const uint4*)(Bp + k);
            pb1 = *(const uint4*)(Bp + sA + k);
            if constexpr (TN == 128) {
                pb2 = *(const uint4*)(Bp + 2 * sA + k);
                pb3 = *(const uint4*)(Bp + 3 * sA + k);
            }
        }
#pragma unroll
        for (int kk = 0; kk < 2; kk++) {
            short8 af[MI], bfr[4];
#pragma unroll
            for (int i = 0; i < MI; i++) af[i]  = *(const short8*)&As[(wm_off + i * 16 + qr) * 64 + cswz[kk]];
#pragma unroll
            for (int j = 0; j < 4; j++)  bfr[j] = *(const short8*)&Bs[(wn_off + j * 16 + qr) * 64 + cswz[kk]];
#pragma unroll
            for (int i = 0; i < MI; i++)
#pragma unroll
                for (int j = 0; j < 4; j++)
                    acc[i][j] = __builtin_amdgcn_mfma_f32_16x16x32_bf16(af[i], bfr[j], acc[i][j], 0, 0, 0);
        }
    }
    // epilogue: C/D layout col=lane&15, row=quad*4+reg
#pragma unroll
    for (int i = 0; i < MI; i++) {
#pragma unroll
        for (int j = 0; j < 4; j++) {
#pragma unroll
            for (int r = 0; r < 4; r++) {
                int row = m0 + wm_off + i * 16 + quad * 4 + r;
                int col = n0 + wn_off + j * 16 + qr;
                size_t idx = (size_t)row * N + col;
                float v = acc[i][j][r];
                if (EPI == 1)      ((unsigned short*)OUT)[idx] = f2b(v);
                else if (EPI == 2) ((float*)OUT)[idx] = RES[idx] + v;
                else {
                    // tanh-form GELU via exp2: g = v*t/(t+1), t = 2^(2u/ln2)
                    float u = v * fmaf(v * v, 0.035677408f, 0.79788456f);
                    float e = fminf(u * 2.885390082f, 80.0f);   // guard inf/inf
                    float t = exp2f(e);
                    float g = v * t / (t + 1.0f);
                    ((unsigned short*)OUT)[idx] = f2b(g);
                }
            }
        }
    }
}

// ---------- MFMA causal flash attention, K-chunk=128, static-max softmax ------
// Register-prefetch pipeline: chunk j+2's global loads issue after the staging
// barrier and overlap chunk j's compute; regs -> LDS next iteration.
// qkv bf16 [4096][3072] (q|k|v blocks of 1024 cols), out bf16 [4096][1024]
__global__ __launch_bounds__(256) void k_attn(
        const unsigned short* __restrict__ qkv, unsigned short* __restrict__ out) {
    __shared__ unsigned short Ks[128][72];      // K rows (Q staged here first)
    __shared__ unsigned short Vt[64][136];      // [dim][key 0..127]
    __shared__ unsigned short Ps[4][16][136];   // per wave [q][key 0..127] (wave-private)

    const float C1 = 0.18033688f;   // 0.125 * log2(e)
    const float C2 = 5.77078016f;   // 4.0   * log2(e)  (static max m=4)

    int l = blockIdx.x;                // 0..1023; big qb dispatched first
    int h = l & 15;
    int qb = 63 - (l >> 4);
    int q0 = qb * 64;

    int tid = threadIdx.x;
    int wave = tid >> 6, lane = tid & 63;
    int lane16 = lane & 15, quad = lane >> 4;

    // ---- stage Q through Ks rows 0..63, read loop-invariant A-frags ----
    {
        int srow = tid >> 2, sc0 = (tid & 3) * 16;
        size_t base = (size_t)(q0 + srow) * 3072 + h * 64 + sc0;
        *(uint4*)&Ks[srow][sc0]     = *(const uint4*)&qkv[base];
        *(uint4*)&Ks[srow][sc0 + 8] = *(const uint4*)&qkv[base + 8];
    }
    __syncthreads();
    short8 aq0 = *(const short8*)&Ks[wave * 16 + lane16][quad * 8];
    short8 aq1 = *(const short8*)&Ks[wave * 16 + lane16][32 + quad * 8];

    f32x4 Oacc[4] = {};                // lane holds O[q=quad*4+r][d=dt*16+lane16]
    float l_part[4] = {0.f, 0.f, 0.f, 0.f};

    int srow = tid >> 1, sc0 = (tid & 1) * 32;   // K staging coords
    int vk = (lane & 31) * 2;                    // V staging: even local key
    int d0 = wave * 16 + (lane >> 5) * 8;

    // prefetch registers (chunk kc): K 4x uint4, V 4x uint4
    uint4 pk0, pk1, pk2, pk3, pv0, pv1, pv2, pv3;
    {   // prefetch chunk 0
        size_t base = (size_t)srow * 3072 + 1024 + h * 64 + sc0;
        pk0 = *(const uint4*)&qkv[base];
        pk1 = *(const uint4*)&qkv[base + 8];
        pk2 = *(const uint4*)&qkv[base + 16];
        pk3 = *(const uint4*)&qkv[base + 24];
        size_t vb0 = (size_t)vk * 3072 + 2048 + h * 64 + d0;
        pv0 = *(const uint4*)&qkv[vb0];
        pv1 = *(const uint4*)&qkv[vb0 + 3072];
        size_t vb1 = (size_t)(64 + vk) * 3072 + 2048 + h * 64 + d0;
        pv2 = *(const uint4*)&qkv[vb1];
        pv3 = *(const uint4*)&qkv[vb1 + 3072];
    }

    for (int kc = 0; kc <= qb; kc += 2) {      // 128 keys per iteration
        __syncthreads();   // prev-iter LDS reads done (covers Q-frag reads at kc=0)
        {   // write prefetched K chunk to LDS
            *(uint4*)&Ks[srow][sc0]      = pk0;
            *(uint4*)&Ks[srow][sc0 + 8]  = pk1;
            *(uint4*)&Ks[srow][sc0 + 16] = pk2;
            *(uint4*)&Ks[srow][sc0 + 24] = pk3;
        }
        {   // write prefetched V chunk TRANSPOSED, key-pairs packed as b32
            const unsigned short* pe0 = (const unsigned short*)&pv0;
            const unsigned short* po0 = (const unsigned short*)&pv1;
            const unsigned short* pe1 = (const unsigned short*)&pv2;
            const unsigned short* po1 = (const unsigned short*)&pv3;
#pragma unroll
            for (int j = 0; j < 8; j++) {
                *(uint32_t*)&Vt[d0 + j][vk]      = (uint32_t)pe0[j] | ((uint32_t)po0[j] << 16);
                *(uint32_t*)&Vt[d0 + j][64 + vk] = (uint32_t)pe1[j] | ((uint32_t)po1[j] << 16);
            }
        }
        __syncthreads();

        if (kc + 2 <= qb) {   // issue next chunk's loads; overlap with compute below
            size_t base = (size_t)((kc + 2) * 64 + srow) * 3072 + 1024 + h * 64 + sc0;
            pk0 = *(const uint4*)&qkv[base];
            pk1 = *(const uint4*)&qkv[base + 8];
            pk2 = *(const uint4*)&qkv[base + 16];
            pk3 = *(const uint4*)&qkv[base + 24];
            size_t vb0 = (size_t)((kc + 2) * 64 + vk) * 3072 + 2048 + h * 64 + d0;
            pv0 = *(const uint4*)&qkv[vb0];
            pv1 = *(const uint4*)&qkv[vb0 + 3072];
            size_t vb1 = (size_t)((kc + 3) * 64 + vk) * 3072 + 2048 + h * 64 + d0;
            pv2 = *(const uint4*)&qkv[vb1];
            pv3 = *(const uint4*)&qkv[vb1 + 3072];
        }

        // ---- S = Q K^T  (16q x 128k per wave) ----
        f32x4 sacc[8] = {};
#pragma unroll
        for (int kt = 0; kt < 8; kt++) {
            short8 bk0 = *(const short8*)&Ks[kt * 16 + lane16][quad * 8];
            short8 bk1 = *(const short8*)&Ks[kt * 16 + lane16][32 + quad * 8];
            sacc[kt] = __builtin_amdgcn_mfma_f32_16x16x32_bf16(aq0, bk0, sacc[kt], 0, 0, 0);
            sacc[kt] = __builtin_amdgcn_mfma_f32_16x16x32_bf16(aq1, bk1, sacc[kt], 0, 0, 0);
        }

        // ---- static-max softmax: p = 2^(s*C1 - C2); mask only on last chunk ----
        bool domask = (kc + 2 > qb);   // wave-uniform
#pragma unroll
        for (int r = 0; r < 4; r++) {
            int qrow = q0 + wave * 16 + quad * 4 + r;
#pragma unroll
            for (int kt = 0; kt < 8; kt++) {
                float s = sacc[kt][r];
                if (domask) {
                    int key = kc * 64 + kt * 16 + lane16;
                    s = (key <= qrow) ? s : -__builtin_inff();
                }
                float p = exp2f(fmaf(s, C1, -C2));   // masked -> 0
                l_part[r] += p;
                Ps[wave][quad * 4 + r][kt * 16 + lane16] = f2b(p);
            }
        }
        // no barrier: Ps is wave-private; in-wave RAW ordered by lgkmcnt

        // ---- O += P V  (A=P rows, B=V^T rows, both key-contiguous) ----
#pragma unroll
        for (int s = 0; s < 4; s++) {
            short8 ap = *(const short8*)&Ps[wave][lane16][s * 32 + quad * 8];
#pragma unroll
            for (int dt = 0; dt < 4; dt++) {
                short8 bv = *(const short8*)&Vt[dt * 16 + lane16][s * 32 + quad * 8];
                Oacc[dt] = __builtin_amdgcn_mfma_f32_16x16x32_bf16(ap, bv, Oacc[dt], 0, 0, 0);
            }
        }
    }

    // deferred l reduction (sum over lane16 key-group) + output
    float invl[4];
#pragma unroll
    for (int r = 0; r < 4; r++) {
        float lf = l_part[r];
        lf += __shfl_xor(lf, 1);
        lf += __shfl_xor(lf, 2);
        lf += __shfl_xor(lf, 4);
        lf += __shfl_xor(lf, 8);
        invl[r] = 1.0f / lf;
    }
#pragma unroll
    for (int dt = 0; dt < 4; dt++) {
#pragma unroll
        for (int r = 0; r < 4; r++) {
            int qrow = q0 + wave * 16 + quad * 4 + r;
            out[(size_t)qrow * 1024 + h * 64 + dt * 16 + lane16] = f2b(Oacc[dt][r] * invl[r]);
        }
    }
}

// ---------- launch ----------
extern "C" void kernel_launch(void* const* d_in, const int* in_sizes, int n_in,
                              void* d_out, int out_size, void* d_ws, size_t ws_size,
                              hipStream_t stream) {
    const float* x      = (const float*)d_in[0];
    const float* w_qkv  = (const float*)d_in[1];
    const float* w_attn = (const float*)d_in[2];
    const float* w_fc   = (const float*)d_in[3];
    const float* w_mlp  = (const float*)d_in[4];
    const float* ln1w   = (const float*)d_in[5];
    const float* ln2w   = (const float*)d_in[6];

    char* ws = (char*)d_ws;   // total 112 MB, no aliasing
    unsigned short* h      = (unsigned short*)(ws + 0);          //  8 MB
    unsigned short* wqkvT  = (unsigned short*)(ws + 8388608);    //  6 MB
    unsigned short* wattnT = (unsigned short*)(ws + 14680064);   //  2 MB
    unsigned short* wfcT   = (unsigned short*)(ws + 16777216);   //  8 MB
    unsigned short* wmlpT  = (unsigned short*)(ws + 25165824);   //  8 MB
    unsigned short* qkv    = (unsigned short*)(ws + 33554432);   // 24 MB
    unsigned short* attno  = (unsigned short*)(ws + 58720256);   //  8 MB
    float*          x2     = (float*)(ws + 67108864);            // 16 MB
    unsigned short* fcact  = (unsigned short*)(ws + 83886080);   // 32 MB
    float* outF = (float*)d_out;

    dim3 tb(32, 8);
    k_transpose_bf16<<<dim3(96, 32),  tb, 0, stream>>>(w_qkv,  wqkvT,  1024, 3072);
    k_transpose_bf16<<<dim3(32, 32),  tb, 0, stream>>>(w_attn, wattnT, 1024, 1024);
    k_transpose_bf16<<<dim3(128, 32), tb, 0, stream>>>(w_fc,   wfcT,   1024, 4096);
    k_transpose_bf16<<<dim3(32, 128), tb, 0, stream>>>(w_mlp,  wmlpT,  4096, 1024);

    k_layernorm<<<4096, 256, 0, stream>>>(x, ln1w, h);
    k_gemm_bt<1, 128><<<dim3(24, 32), 256, 0, stream>>>(h, wqkvT, nullptr, qkv, 4096, 3072, 1024);
    k_attn<<<1024, 256, 0, stream>>>(qkv, attno);
    k_gemm_bt<2, 64><<<dim3(16, 32), 256, 0, stream>>>(attno, wattnT, x, x2, 4096, 1024, 1024);
    k_layernorm<<<4096, 256, 0, stream>>>(x2, ln2w, h);
    k_gemm_bt<3, 128><<<dim3(32, 32), 256, 0, stream>>>(h, wfcT, nullptr, fcact, 4096, 4096, 1024);
    k_gemm_bt<2, 64><<<dim3(16, 32), 256, 0, stream>>>(fcact, wmlpT, x2, outF, 4096, 1024, 4096);
}

// Round 11
// 366.713 us; speedup vs baseline: 2.0463x; 1.0132x over previous
//
#include <hip/hip_runtime.h>
#include <cstdint>

// ---------- helpers ----------
typedef __attribute__((ext_vector_type(8))) short short8;   // 8 x bf16 (4 VGPRs)
typedef __attribute__((ext_vector_type(4))) float f32x4;

__device__ __forceinline__ float b2f(unsigned short u) {
    return __uint_as_float(((unsigned int)u) << 16);
}
__device__ __forceinline__ unsigned short f2b(float f) {   // RNE f32->bf16
    unsigned int u = __float_as_uint(f);
    u += 0x7FFFu + ((u >> 16) & 1u);
    return (unsigned short)(u >> 16);
}

// ---------- fused transpose + fp32->bf16 convert for all 4 weights ----------
// w[K][N] -> wT[N][K]; tile ranges: [0,3072) wqkv, [3072,4096) wattn,
// [4096,8192) wfc, [8192,12288) wmlp. Block (32,8).
__global__ __launch_bounds__(256) void k_transpose_all(
        const float* __restrict__ w0, const float* __restrict__ w1,
        const float* __restrict__ w2, const float* __restrict__ w3,
        unsigned short* __restrict__ o0, unsigned short* __restrict__ o1,
        unsigned short* __restrict__ o2, unsigned short* __restrict__ o3) {
    __shared__ float tile[32][33];
    int b = blockIdx.x;
    const float* w; unsigned short* o; int K, N, nx, tb;
    if (b < 3072)      { w = w0; o = o0; K = 1024; N = 3072; nx = 96;  tb = b; }
    else if (b < 4096) { w = w1; o = o1; K = 1024; N = 1024; nx = 32;  tb = b - 3072; }
    else if (b < 8192) { w = w2; o = o2; K = 1024; N = 4096; nx = 128; tb = b - 4096; }
    else               { w = w3; o = o3; K = 4096; N = 1024; nx = 32;  tb = b - 8192; }
    int n0 = (tb % nx) * 32, k0 = (tb / nx) * 32;
    int tx = threadIdx.x, ty = threadIdx.y;
#pragma unroll
    for (int i = 0; i < 4; i++)
        tile[ty + 8 * i][tx] = w[(size_t)(k0 + ty + 8 * i) * N + n0 + tx];
    __syncthreads();
#pragma unroll
    for (int i = 0; i < 4; i++)
        o[(size_t)(n0 + ty + 8 * i) * K + k0 + tx] = f2b(tile[tx][ty + 8 * i]);
}

// ---------- layernorm (fp32 in, bf16 out), one row (C=1024) per block ----------
__global__ __launch_bounds__(256) void k_layernorm(
        const float* __restrict__ x, const float* __restrict__ w,
        unsigned short* __restrict__ out) {
    int row = blockIdx.x, tid = threadIdx.x;
    const float4* xr = (const float4*)(x + (size_t)row * 1024);
    float4 v = xr[tid];
    float s  = v.x + v.y + v.z + v.w;
    float ss = v.x * v.x + v.y * v.y + v.z * v.z + v.w * v.w;
#pragma unroll
    for (int off = 32; off >= 1; off >>= 1) {
        s  += __shfl_down(s, off);
        ss += __shfl_down(ss, off);
    }
    __shared__ float red[10];
    if ((tid & 63) == 0) { red[tid >> 6] = s; red[4 + (tid >> 6)] = ss; }
    __syncthreads();
    if (tid == 0) {
        float S  = red[0] + red[1] + red[2] + red[3];
        float SS = red[4] + red[5] + red[6] + red[7];
        float mu  = S * (1.0f / 1024.0f);
        float var = SS * (1.0f / 1024.0f) - mu * mu;
        red[8] = mu; red[9] = rsqrtf(var + 1e-5f);
    }
    __syncthreads();
    float mu = red[8], rs = red[9];
    float4 wv = ((const float4*)w)[tid];
    ushort4 pk;
    pk.x = f2b((v.x - mu) * rs * wv.x);
    pk.y = f2b((v.y - mu) * rs * wv.y);
    pk.z = f2b((v.z - mu) * rs * wv.z);
    pk.w = f2b((v.w - mu) * rs * wv.w);
    *(ushort4*)(out + (size_t)row * 1024 + tid * 4) = pk;
}

// ---------- bf16 MFMA GEMM: C[M][N] = A[M][K] @ BT[N][K]^T (+ epilogue) ----------
// BK=64, column-rotate LDS swizzle (0 conflicts measured), named-scalar VGPR
// register-prefetch pipeline (arrays spill — R9), __launch_bounds__(256,2).
// EPI: 1 = store bf16, 2 = RES + acc -> f32, 3 = gelu(acc) -> bf16
// TN: 128 (4 waves 64x64) or 64 (4 waves 32x64)
template <int EPI, int TN>
__global__ __launch_bounds__(256, 2) void k_gemm_bt(
        const unsigned short* __restrict__ A, const unsigned short* __restrict__ BT,
        const float* __restrict__ RES, void* __restrict__ OUT,
        int M, int N, int K) {
    constexpr int MI = (TN == 128) ? 4 : 2;        // m-subtiles per wave
    __shared__ __align__(16) unsigned short As[128 * 64];
    __shared__ __align__(16) unsigned short Bs[TN * 64];
    int tid  = threadIdx.x;
    int lane = tid & 63, wave = tid >> 6;
    int quad = lane >> 4, qr = lane & 15;
    int wm_off = (TN == 128) ? (wave >> 1) * 64 : wave * 32;
    int wn_off = (TN == 128) ? (wave & 1) * 64 : 0;
    int m0 = blockIdx.y * 128, n0 = blockIdx.x * TN;
    int r0 = tid >> 3;                      // 0..31
    int c0 = (tid & 7) * 8;
    int cs = 8 * (((tid & 7) + (r0 & 7)) & 7);
    int cswz[2];
#pragma unroll
    for (int kk = 0; kk < 2; kk++) cswz[kk] = 8 * (((kk * 4) + quad + (qr & 7)) & 7);

    const unsigned short* Ap = A  + (size_t)(m0 + r0) * K + c0;
    const unsigned short* Bp = BT + (size_t)(n0 + r0) * K + c0;
    const size_t sA = (size_t)32 * K;

    uint4 pa0, pa1, pa2, pa3, pb0, pb1, pb2, pb3;
    pa0 = *(const uint4*)(Ap);
    pa1 = *(const uint4*)(Ap + sA);
    pa2 = *(const uint4*)(Ap + 2 * sA);
    pa3 = *(const uint4*)(Ap + 3 * sA);
    pb0 = *(const uint4*)(Bp);
    pb1 = *(const uint4*)(Bp + sA);
    if constexpr (TN == 128) {
        pb2 = *(const uint4*)(Bp + 2 * sA);
        pb3 = *(const uint4*)(Bp + 3 * sA);
    }

    f32x4 acc[MI][4] = {};
    for (int k0 = 0; k0 < K; k0 += 64) {
        __syncthreads();   // prev compute's LDS reads done
        *(uint4*)&As[(r0)      * 64 + cs] = pa0;
        *(uint4*)&As[(32 + r0) * 64 + cs] = pa1;
        *(uint4*)&As[(64 + r0) * 64 + cs] = pa2;
        *(uint4*)&As[(96 + r0) * 64 + cs] = pa3;
        *(uint4*)&Bs[(r0)      * 64 + cs] = pb0;
        *(uint4*)&Bs[(32 + r0) * 64 + cs] = pb1;
        if constexpr (TN == 128) {
            *(uint4*)&Bs[(64 + r0) * 64 + cs] = pb2;
            *(uint4*)&Bs[(96 + r0) * 64 + cs] = pb3;
        }
        __syncthreads();
        if (k0 + 64 < K) {   // prefetch next slab; vmcnt waits land next iteration
            int k = k0 + 64;
            pa0 = *(const uint4*)(Ap + k);
            pa1 = *(const uint4*)(Ap + sA + k);
            pa2 = *(const uint4*)(Ap + 2 * sA + k);
            pa3 = *(const uint4*)(Ap + 3 * sA + k);
            pb0 = *(const uint4*)(Bp + k);
            pb1 = *(const uint4*)(Bp + sA + k);
            if constexpr (TN == 128) {
                pb2 = *(const uint4*)(Bp + 2 * sA + k);
                pb3 = *(const uint4*)(Bp + 3 * sA + k);
            }
        }
#pragma unroll
        for (int kk = 0; kk < 2; kk++) {
            short8 af[MI], bfr[4];
#pragma unroll
            for (int i = 0; i < MI; i++) af[i]  = *(const short8*)&As[(wm_off + i * 16 + qr) * 64 + cswz[kk]];
#pragma unroll
            for (int j = 0; j < 4; j++)  bfr[j] = *(const short8*)&Bs[(wn_off + j * 16 + qr) * 64 + cswz[kk]];
#pragma unroll
            for (int i = 0; i < MI; i++)
#pragma unroll
                for (int j = 0; j < 4; j++)
                    acc[i][j] = __builtin_amdgcn_mfma_f32_16x16x32_bf16(af[i], bfr[j], acc[i][j], 0, 0, 0);
        }
    }
    // epilogue: C/D layout col=lane&15, row=quad*4+reg
#pragma unroll
    for (int i = 0; i < MI; i++) {
#pragma unroll
        for (int j = 0; j < 4; j++) {
#pragma unroll
            for (int r = 0; r < 4; r++) {
                int row = m0 + wm_off + i * 16 + quad * 4 + r;
                int col = n0 + wn_off + j * 16 + qr;
                size_t idx = (size_t)row * N + col;
                float v = acc[i][j][r];
                if (EPI == 1)      ((unsigned short*)OUT)[idx] = f2b(v);
                else if (EPI == 2) ((float*)OUT)[idx] = RES[idx] + v;
                else {
                    // tanh-form GELU via exp2: g = v*t/(t+1), t = 2^(2u/ln2)
                    float u = v * fmaf(v * v, 0.035677408f, 0.79788456f);
                    float e = fminf(u * 2.885390082f, 80.0f);   // guard inf/inf
                    float t = exp2f(e);
                    float g = v * t / (t + 1.0f);
                    ((unsigned short*)OUT)[idx] = f2b(g);
                }
            }
        }
    }
}

// ---------- MFMA causal flash attention, K-chunk=128, static-max softmax ------
// Register-prefetch pipeline: chunk j+2's global loads issue after the staging
// barrier and overlap chunk j's compute; regs -> LDS next iteration.
// Ps stored via TRUNCATED bf16 (1 VALU vs 4 for RNE; P in [0,1] feeding a
// normalized sum -> bias <= 0.2%, far under threshold).
// qkv bf16 [4096][3072] (q|k|v blocks of 1024 cols), out bf16 [4096][1024]
__global__ __launch_bounds__(256) void k_attn(
        const unsigned short* __restrict__ qkv, unsigned short* __restrict__ out) {
    __shared__ unsigned short Ks[128][72];      // K rows (Q staged here first)
    __shared__ unsigned short Vt[64][136];      // [dim][key 0..127]
    __shared__ unsigned short Ps[4][16][136];   // per wave [q][key 0..127] (wave-private)

    const float C1 = 0.18033688f;   // 0.125 * log2(e)
    const float C2 = 5.77078016f;   // 4.0   * log2(e)  (static max m=4)

    int l = blockIdx.x;                // 0..1023; big qb dispatched first
    int h = l & 15;
    int qb = 63 - (l >> 4);
    int q0 = qb * 64;

    int tid = threadIdx.x;
    int wave = tid >> 6, lane = tid & 63;
    int lane16 = lane & 15, quad = lane >> 4;

    // ---- stage Q through Ks rows 0..63, read loop-invariant A-frags ----
    {
        int srow = tid >> 2, sc0 = (tid & 3) * 16;
        size_t base = (size_t)(q0 + srow) * 3072 + h * 64 + sc0;
        *(uint4*)&Ks[srow][sc0]     = *(const uint4*)&qkv[base];
        *(uint4*)&Ks[srow][sc0 + 8] = *(const uint4*)&qkv[base + 8];
    }
    __syncthreads();
    short8 aq0 = *(const short8*)&Ks[wave * 16 + lane16][quad * 8];
    short8 aq1 = *(const short8*)&Ks[wave * 16 + lane16][32 + quad * 8];

    f32x4 Oacc[4] = {};                // lane holds O[q=quad*4+r][d=dt*16+lane16]
    float l_part[4] = {0.f, 0.f, 0.f, 0.f};

    int srow = tid >> 1, sc0 = (tid & 1) * 32;   // K staging coords
    int vk = (lane & 31) * 2;                    // V staging: even local key
    int d0 = wave * 16 + (lane >> 5) * 8;

    // prefetch registers (chunk kc): K 4x uint4, V 4x uint4
    uint4 pk0, pk1, pk2, pk3, pv0, pv1, pv2, pv3;
    {   // prefetch chunk 0
        size_t base = (size_t)srow * 3072 + 1024 + h * 64 + sc0;
        pk0 = *(const uint4*)&qkv[base];
        pk1 = *(const uint4*)&qkv[base + 8];
        pk2 = *(const uint4*)&qkv[base + 16];
        pk3 = *(const uint4*)&qkv[base + 24];
        size_t vb0 = (size_t)vk * 3072 + 2048 + h * 64 + d0;
        pv0 = *(const uint4*)&qkv[vb0];
        pv1 = *(const uint4*)&qkv[vb0 + 3072];
        size_t vb1 = (size_t)(64 + vk) * 3072 + 2048 + h * 64 + d0;
        pv2 = *(const uint4*)&qkv[vb1];
        pv3 = *(const uint4*)&qkv[vb1 + 3072];
    }

    for (int kc = 0; kc <= qb; kc += 2) {      // 128 keys per iteration
        __syncthreads();   // prev-iter LDS reads done (covers Q-frag reads at kc=0)
        {   // write prefetched K chunk to LDS
            *(uint4*)&Ks[srow][sc0]      = pk0;
            *(uint4*)&Ks[srow][sc0 + 8]  = pk1;
            *(uint4*)&Ks[srow][sc0 + 16] = pk2;
            *(uint4*)&Ks[srow][sc0 + 24] = pk3;
        }
        {   // write prefetched V chunk TRANSPOSED, key-pairs packed as b32
            const unsigned short* pe0 = (const unsigned short*)&pv0;
            const unsigned short* po0 = (const unsigned short*)&pv1;
            const unsigned short* pe1 = (const unsigned short*)&pv2;
            const unsigned short* po1 = (const unsigned short*)&pv3;
#pragma unroll
            for (int j = 0; j < 8; j++) {
                *(uint32_t*)&Vt[d0 + j][vk]      = (uint32_t)pe0[j] | ((uint32_t)po0[j] << 16);
                *(uint32_t*)&Vt[d0 + j][64 + vk] = (uint32_t)pe1[j] | ((uint32_t)po1[j] << 16);
            }
        }
        __syncthreads();

        if (kc + 2 <= qb) {   // issue next chunk's loads; overlap with compute below
            size_t base = (size_t)((kc + 2) * 64 + srow) * 3072 + 1024 + h * 64 + sc0;
            pk0 = *(const uint4*)&qkv[base];
            pk1 = *(const uint4*)&qkv[base + 8];
            pk2 = *(const uint4*)&qkv[base + 16];
            pk3 = *(const uint4*)&qkv[base + 24];
            size_t vb0 = (size_t)((kc + 2) * 64 + vk) * 3072 + 2048 + h * 64 + d0;
            pv0 = *(const uint4*)&qkv[vb0];
            pv1 = *(const uint4*)&qkv[vb0 + 3072];
            size_t vb1 = (size_t)((kc + 3) * 64 + vk) * 3072 + 2048 + h * 64 + d0;
            pv2 = *(const uint4*)&qkv[vb1];
            pv3 = *(const uint4*)&qkv[vb1 + 3072];
        }

        // ---- S = Q K^T  (16q x 128k per wave) ----
        f32x4 sacc[8] = {};
#pragma unroll
        for (int kt = 0; kt < 8; kt++) {
            short8 bk0 = *(const short8*)&Ks[kt * 16 + lane16][quad * 8];
            short8 bk1 = *(const short8*)&Ks[kt * 16 + lane16][32 + quad * 8];
            sacc[kt] = __builtin_amdgcn_mfma_f32_16x16x32_bf16(aq0, bk0, sacc[kt], 0, 0, 0);
            sacc[kt] = __builtin_amdgcn_mfma_f32_16x16x32_bf16(aq1, bk1, sacc[kt], 0, 0, 0);
        }

        // ---- static-max softmax: p = 2^(s*C1 - C2); mask only on last chunk ----
        bool domask = (kc + 2 > qb);   // wave-uniform
#pragma unroll
        for (int r = 0; r < 4; r++) {
            int qrow = q0 + wave * 16 + quad * 4 + r;
#pragma unroll
            for (int kt = 0; kt < 8; kt++) {
                float s = sacc[kt][r];
                if (domask) {
                    int key = kc * 64 + kt * 16 + lane16;
                    s = (key <= qrow) ? s : -__builtin_inff();
                }
                float p = exp2f(fmaf(s, C1, -C2));   // masked -> 0
                l_part[r] += p;
                Ps[wave][quad * 4 + r][kt * 16 + lane16] =
                    (unsigned short)(__float_as_uint(p) >> 16);   // truncated bf16
            }
        }
        // no barrier: Ps is wave-private; in-wave RAW ordered by lgkmcnt

        // ---- O += P V  (A=P rows, B=V^T rows, both key-contiguous) ----
#pragma unroll
        for (int s = 0; s < 4; s++) {
            short8 ap = *(const short8*)&Ps[wave][lane16][s * 32 + quad * 8];
#pragma unroll
            for (int dt = 0; dt < 4; dt++) {
                short8 bv = *(const short8*)&Vt[dt * 16 + lane16][s * 32 + quad * 8];
                Oacc[dt] = __builtin_amdgcn_mfma_f32_16x16x32_bf16(ap, bv, Oacc[dt], 0, 0, 0);
            }
        }
    }

    // deferred l reduction (sum over lane16 key-group) + output
    float invl[4];
#pragma unroll
    for (int r = 0; r < 4; r++) {
        float lf = l_part[r];
        lf += __shfl_xor(lf, 1);
        lf += __shfl_xor(lf, 2);
        lf += __shfl_xor(lf, 4);
        lf += __shfl_xor(lf, 8);
        invl[r] = 1.0f / lf;
    }
#pragma unroll
    for (int dt = 0; dt < 4; dt++) {
#pragma unroll
        for (int r = 0; r < 4; r++) {
            int qrow = q0 + wave * 16 + quad * 4 + r;
            out[(size_t)qrow * 1024 + h * 64 + dt * 16 + lane16] = f2b(Oacc[dt][r] * invl[r]);
        }
    }
}

// ---------- launch ----------
extern "C" void kernel_launch(void* const* d_in, const int* in_sizes, int n_in,
                              void* d_out, int out_size, void* d_ws, size_t ws_size,
                              hipStream_t stream) {
    const float* x      = (const float*)d_in[0];
    const float* w_qkv  = (const float*)d_in[1];
    const float* w_attn = (const float*)d_in[2];
    const float* w_fc   = (const float*)d_in[3];
    const float* w_mlp  = (const float*)d_in[4];
    const float* ln1w   = (const float*)d_in[5];
    const float* ln2w   = (const float*)d_in[6];

    char* ws = (char*)d_ws;   // total 112 MB, no aliasing
    unsigned short* h      = (unsigned short*)(ws + 0);          //  8 MB
    unsigned short* wqkvT  = (unsigned short*)(ws + 8388608);    //  6 MB
    unsigned short* wattnT = (unsigned short*)(ws + 14680064);   //  2 MB
    unsigned short* wfcT   = (unsigned short*)(ws + 16777216);   //  8 MB
    unsigned short* wmlpT  = (unsigned short*)(ws + 25165824);   //  8 MB
    unsigned short* qkv    = (unsigned short*)(ws + 33554432);   // 24 MB
    unsigned short* attno  = (unsigned short*)(ws + 58720256);   //  8 MB
    float*          x2     = (float*)(ws + 67108864);            // 16 MB
    unsigned short* fcact  = (unsigned short*)(ws + 83886080);   // 32 MB
    float* outF = (float*)d_out;

    k_transpose_all<<<12288, dim3(32, 8), 0, stream>>>(
        w_qkv, w_attn, w_fc, w_mlp, wqkvT, wattnT, wfcT, wmlpT);

    k_layernorm<<<4096, 256, 0, stream>>>(x, ln1w, h);
    k_gemm_bt<1, 128><<<dim3(24, 32), 256, 0, stream>>>(h, wqkvT, nullptr, qkv, 4096, 3072, 1024);
    k_attn<<<1024, 256, 0, stream>>>(qkv, attno);
    k_gemm_bt<2, 64><<<dim3(16, 32), 256, 0, stream>>>(attno, wattnT, x, x2, 4096, 1024, 1024);
    k_layernorm<<<4096, 256, 0, stream>>>(x2, ln2w, h);
    k_gemm_bt<3, 128><<<dim3(32, 32), 256, 0, stream>>>(h, wfcT, nullptr, fcact, 4096, 4096, 1024);
    k_gemm_bt<2, 64><<<dim3(16, 32), 256, 0, stream>>>(fcact, wmlpT, x2, outF, 4096, 1024, 4096);
}

// Round 12
// 365.144 us; speedup vs baseline: 2.0551x; 1.0043x over previous
//
#include <hip/hip_runtime.h>
#include <cstdint>

// ---------- helpers ----------
typedef __attribute__((ext_vector_type(8))) short short8;   // 8 x bf16 (4 VGPRs)
typedef __attribute__((ext_vector_type(4))) float f32x4;

__device__ __forceinline__ float b2f(unsigned short u) {
    return __uint_as_float(((unsigned int)u) << 16);
}
__device__ __forceinline__ unsigned short f2b(float f) {   // RNE f32->bf16
    unsigned int u = __float_as_uint(f);
    u += 0x7FFFu + ((u >> 16) & 1u);
    return (unsigned short)(u >> 16);
}

// ---------- fused transpose + fp32->bf16 convert for all 4 weights ----------
__global__ __launch_bounds__(256) void k_transpose_all(
        const float* __restrict__ w0, const float* __restrict__ w1,
        const float* __restrict__ w2, const float* __restrict__ w3,
        unsigned short* __restrict__ o0, unsigned short* __restrict__ o1,
        unsigned short* __restrict__ o2, unsigned short* __restrict__ o3) {
    __shared__ float tile[32][33];
    int b = blockIdx.x;
    const float* w; unsigned short* o; int K, N, nx, tb;
    if (b < 3072)      { w = w0; o = o0; K = 1024; N = 3072; nx = 96;  tb = b; }
    else if (b < 4096) { w = w1; o = o1; K = 1024; N = 1024; nx = 32;  tb = b - 3072; }
    else if (b < 8192) { w = w2; o = o2; K = 1024; N = 4096; nx = 128; tb = b - 4096; }
    else               { w = w3; o = o3; K = 4096; N = 1024; nx = 32;  tb = b - 8192; }
    int n0 = (tb % nx) * 32, k0 = (tb / nx) * 32;
    int tx = threadIdx.x, ty = threadIdx.y;
#pragma unroll
    for (int i = 0; i < 4; i++)
        tile[ty + 8 * i][tx] = w[(size_t)(k0 + ty + 8 * i) * N + n0 + tx];
    __syncthreads();
#pragma unroll
    for (int i = 0; i < 4; i++)
        o[(size_t)(n0 + ty + 8 * i) * K + k0 + tx] = f2b(tile[tx][ty + 8 * i]);
}

// ---------- layernorm (fp32 in, bf16 out), one row (C=1024) per block ----------
__global__ __launch_bounds__(256) void k_layernorm(
        const float* __restrict__ x, const float* __restrict__ w,
        unsigned short* __restrict__ out) {
    int row = blockIdx.x, tid = threadIdx.x;
    const float4* xr = (const float4*)(x + (size_t)row * 1024);
    float4 v = xr[tid];
    float s  = v.x + v.y + v.z + v.w;
    float ss = v.x * v.x + v.y * v.y + v.z * v.z + v.w * v.w;
#pragma unroll
    for (int off = 32; off >= 1; off >>= 1) {
        s  += __shfl_down(s, off);
        ss += __shfl_down(ss, off);
    }
    __shared__ float red[10];
    if ((tid & 63) == 0) { red[tid >> 6] = s; red[4 + (tid >> 6)] = ss; }
    __syncthreads();
    if (tid == 0) {
        float S  = red[0] + red[1] + red[2] + red[3];
        float SS = red[4] + red[5] + red[6] + red[7];
        float mu  = S * (1.0f / 1024.0f);
        float var = SS * (1.0f / 1024.0f) - mu * mu;
        red[8] = mu; red[9] = rsqrtf(var + 1e-5f);
    }
    __syncthreads();
    float mu = red[8], rs = red[9];
    float4 wv = ((const float4*)w)[tid];
    ushort4 pk;
    pk.x = f2b((v.x - mu) * rs * wv.x);
    pk.y = f2b((v.y - mu) * rs * wv.y);
    pk.z = f2b((v.z - mu) * rs * wv.z);
    pk.w = f2b((v.w - mu) * rs * wv.w);
    *(ushort4*)(out + (size_t)row * 1024 + tid * 4) = pk;
}

// ---------- bf16 MFMA GEMM: C[M][N] = A[M][K] @ BT[N][K]^T (+ epilogue) ----------
// BK=64, column-rotate LDS swizzle (0 conflicts), named-scalar VGPR prefetch.
// TM=128/TN=128: 2x2 waves of 64x64, 3 blocks/CU.
// TM=64/TN=64:   2x2 waves of 32x32, 4 blocks/CU (latency-bound proj GEMMs).
// EPI: 1 = store bf16, 2 = RES + acc -> f32, 3 = gelu(acc) -> bf16
template <int EPI, int TM, int TN, int MINW>
__global__ __launch_bounds__(256, MINW) void k_gemm_bt(
        const unsigned short* __restrict__ A, const unsigned short* __restrict__ BT,
        const float* __restrict__ RES, void* __restrict__ OUT,
        int M, int N, int K) {
    constexpr int WT = (TM == 128) ? 64 : 32;      // wave tile (square)
    constexpr int MI = WT / 16;                    // subtiles per wave (each dim)
    constexpr int NA = TM / 32, NB = TN / 32;      // staging uint4-chunks per thread
    __shared__ __align__(16) unsigned short As[TM * 64];
    __shared__ __align__(16) unsigned short Bs[TN * 64];
    int tid  = threadIdx.x;
    int lane = tid & 63, wave = tid >> 6;
    int quad = lane >> 4, qr = lane & 15;
    int wm_off = (wave >> 1) * WT;
    int wn_off = (wave & 1) * WT;
    int m0 = blockIdx.y * TM, n0 = blockIdx.x * TN;
    int r0 = tid >> 3;                      // 0..31
    int c0 = (tid & 7) * 8;
    int cs = 8 * (((tid & 7) + (r0 & 7)) & 7);
    int cswz[2];
#pragma unroll
    for (int kk = 0; kk < 2; kk++) cswz[kk] = 8 * (((kk * 4) + quad + (qr & 7)) & 7);

    const unsigned short* Ap = A  + (size_t)(m0 + r0) * K + c0;
    const unsigned short* Bp = BT + (size_t)(n0 + r0) * K + c0;
    const size_t sA = (size_t)32 * K;

    uint4 pa0, pa1, pa2, pa3, pb0, pb1, pb2, pb3;
    pa0 = *(const uint4*)(Ap);
    pa1 = *(const uint4*)(Ap + sA);
    if constexpr (NA == 4) {
        pa2 = *(const uint4*)(Ap + 2 * sA);
        pa3 = *(const uint4*)(Ap + 3 * sA);
    }
    pb0 = *(const uint4*)(Bp);
    pb1 = *(const uint4*)(Bp + sA);
    if constexpr (NB == 4) {
        pb2 = *(const uint4*)(Bp + 2 * sA);
        pb3 = *(const uint4*)(Bp + 3 * sA);
    }

    f32x4 acc[MI][MI] = {};
    for (int k0 = 0; k0 < K; k0 += 64) {
        __syncthreads();   // prev compute's LDS reads done
        *(uint4*)&As[(r0)      * 64 + cs] = pa0;
        *(uint4*)&As[(32 + r0) * 64 + cs] = pa1;
        if constexpr (NA == 4) {
            *(uint4*)&As[(64 + r0) * 64 + cs] = pa2;
            *(uint4*)&As[(96 + r0) * 64 + cs] = pa3;
        }
        *(uint4*)&Bs[(r0)      * 64 + cs] = pb0;
        *(uint4*)&Bs[(32 + r0) * 64 + cs] = pb1;
        if constexpr (NB == 4) {
            *(uint4*)&Bs[(64 + r0) * 64 + cs] = pb2;
            *(uint4*)&Bs[(96 + r0) * 64 + cs] = pb3;
        }
        __syncthreads();
        if (k0 + 64 < K) {   // prefetch next slab; vmcnt waits land next iteration
            int k = k0 + 64;
            pa0 = *(const uint4*)(Ap + k);
            pa1 = *(const uint4*)(Ap + sA + k);
            if constexpr (NA == 4) {
                pa2 = *(const uint4*)(Ap + 2 * sA + k);
                pa3 = *(const uint4*)(Ap + 3 * sA + k);
            }
            pb0 = *(const uint4*)(Bp + k);
            pb1 = *(const uint4*)(Bp + sA + k);
            if constexpr (NB == 4) {
                pb2 = *(const uint4*)(Bp + 2 * sA + k);
                pb3 = *(const uint4*)(Bp + 3 * sA + k);
            }
        }
#pragma unroll
        for (int kk = 0; kk < 2; kk++) {
            short8 af[MI], bfr[MI];
#pragma unroll
            for (int i = 0; i < MI; i++) af[i]  = *(const short8*)&As[(wm_off + i * 16 + qr) * 64 + cswz[kk]];
#pragma unroll
            for (int j = 0; j < MI; j++) bfr[j] = *(const short8*)&Bs[(wn_off + j * 16 + qr) * 64 + cswz[kk]];
#pragma unroll
            for (int i = 0; i < MI; i++)
#pragma unroll
                for (int j = 0; j < MI; j++)
                    acc[i][j] = __builtin_amdgcn_mfma_f32_16x16x32_bf16(af[i], bfr[j], acc[i][j], 0, 0, 0);
        }
    }
    // epilogue: C/D layout col=lane&15, row=quad*4+reg
#pragma unroll
    for (int i = 0; i < MI; i++) {
#pragma unroll
        for (int j = 0; j < MI; j++) {
#pragma unroll
            for (int r = 0; r < 4; r++) {
                int row = m0 + wm_off + i * 16 + quad * 4 + r;
                int col = n0 + wn_off + j * 16 + qr;
                size_t idx = (size_t)row * N + col;
                float v = acc[i][j][r];
                if (EPI == 1)      ((unsigned short*)OUT)[idx] = f2b(v);
                else if (EPI == 2) ((float*)OUT)[idx] = RES[idx] + v;
                else {
                    // tanh-form GELU via exp2: g = v*t/(t+1), t = 2^(2u/ln2)
                    float u = v * fmaf(v * v, 0.035677408f, 0.79788456f);
                    float e = fminf(u * 2.885390082f, 80.0f);   // guard inf/inf
                    float t = exp2f(e);
                    float g = v * t / (t + 1.0f);
                    ((unsigned short*)OUT)[idx] = f2b(g);
                }
            }
        }
    }
}

// ---------- MFMA causal flash attention, K-chunk=128, static-max softmax ------
// Register-prefetch pipeline; Ps via truncated bf16. (byte-identical to R11)
__global__ __launch_bounds__(256) void k_attn(
        const unsigned short* __restrict__ qkv, unsigned short* __restrict__ out) {
    __shared__ unsigned short Ks[128][72];      // K rows (Q staged here first)
    __shared__ unsigned short Vt[64][136];      // [dim][key 0..127]
    __shared__ unsigned short Ps[4][16][136];   // per wave [q][key 0..127] (wave-private)

    const float C1 = 0.18033688f;   // 0.125 * log2(e)
    const float C2 = 5.77078016f;   // 4.0   * log2(e)  (static max m=4)

    int l = blockIdx.x;                // 0..1023; big qb dispatched first
    int h = l & 15;
    int qb = 63 - (l >> 4);
    int q0 = qb * 64;

    int tid = threadIdx.x;
    int wave = tid >> 6, lane = tid & 63;
    int lane16 = lane & 15, quad = lane >> 4;

    // ---- stage Q through Ks rows 0..63, read loop-invariant A-frags ----
    {
        int srow = tid >> 2, sc0 = (tid & 3) * 16;
        size_t base = (size_t)(q0 + srow) * 3072 + h * 64 + sc0;
        *(uint4*)&Ks[srow][sc0]     = *(const uint4*)&qkv[base];
        *(uint4*)&Ks[srow][sc0 + 8] = *(const uint4*)&qkv[base + 8];
    }
    __syncthreads();
    short8 aq0 = *(const short8*)&Ks[wave * 16 + lane16][quad * 8];
    short8 aq1 = *(const short8*)&Ks[wave * 16 + lane16][32 + quad * 8];

    f32x4 Oacc[4] = {};                // lane holds O[q=quad*4+r][d=dt*16+lane16]
    float l_part[4] = {0.f, 0.f, 0.f, 0.f};

    int srow = tid >> 1, sc0 = (tid & 1) * 32;   // K staging coords
    int vk = (lane & 31) * 2;                    // V staging: even local key
    int d0 = wave * 16 + (lane >> 5) * 8;

    // prefetch registers (chunk kc): K 4x uint4, V 4x uint4
    uint4 pk0, pk1, pk2, pk3, pv0, pv1, pv2, pv3;
    {   // prefetch chunk 0
        size_t base = (size_t)srow * 3072 + 1024 + h * 64 + sc0;
        pk0 = *(const uint4*)&qkv[base];
        pk1 = *(const uint4*)&qkv[base + 8];
        pk2 = *(const uint4*)&qkv[base + 16];
        pk3 = *(const uint4*)&qkv[base + 24];
        size_t vb0 = (size_t)vk * 3072 + 2048 + h * 64 + d0;
        pv0 = *(const uint4*)&qkv[vb0];
        pv1 = *(const uint4*)&qkv[vb0 + 3072];
        size_t vb1 = (size_t)(64 + vk) * 3072 + 2048 + h * 64 + d0;
        pv2 = *(const uint4*)&qkv[vb1];
        pv3 = *(const uint4*)&qkv[vb1 + 3072];
    }

    for (int kc = 0; kc <= qb; kc += 2) {      // 128 keys per iteration
        __syncthreads();   // prev-iter LDS reads done (covers Q-frag reads at kc=0)
        {   // write prefetched K chunk to LDS
            *(uint4*)&Ks[srow][sc0]      = pk0;
            *(uint4*)&Ks[srow][sc0 + 8]  = pk1;
            *(uint4*)&Ks[srow][sc0 + 16] = pk2;
            *(uint4*)&Ks[srow][sc0 + 24] = pk3;
        }
        {   // write prefetched V chunk TRANSPOSED, key-pairs packed as b32
            const unsigned short* pe0 = (const unsigned short*)&pv0;
            const unsigned short* po0 = (const unsigned short*)&pv1;
            const unsigned short* pe1 = (const unsigned short*)&pv2;
            const unsigned short* po1 = (const unsigned short*)&pv3;
#pragma unroll
            for (int j = 0; j < 8; j++) {
                *(uint32_t*)&Vt[d0 + j][vk]      = (uint32_t)pe0[j] | ((uint32_t)po0[j] << 16);
                *(uint32_t*)&Vt[d0 + j][64 + vk] = (uint32_t)pe1[j] | ((uint32_t)po1[j] << 16);
            }
        }
        __syncthreads();

        if (kc + 2 <= qb) {   // issue next chunk's loads; overlap with compute below
            size_t base = (size_t)((kc + 2) * 64 + srow) * 3072 + 1024 + h * 64 + sc0;
            pk0 = *(const uint4*)&qkv[base];
            pk1 = *(const uint4*)&qkv[base + 8];
            pk2 = *(const uint4*)&qkv[base + 16];
            pk3 = *(const uint4*)&qkv[base + 24];
            size_t vb0 = (size_t)((kc + 2) * 64 + vk) * 3072 + 2048 + h * 64 + d0;
            pv0 = *(const uint4*)&qkv[vb0];
            pv1 = *(const uint4*)&qkv[vb0 + 3072];
            size_t vb1 = (size_t)((kc + 3) * 64 + vk) * 3072 + 2048 + h * 64 + d0;
            pv2 = *(const uint4*)&qkv[vb1];
            pv3 = *(const uint4*)&qkv[vb1 + 3072];
        }

        // ---- S = Q K^T  (16q x 128k per wave) ----
        f32x4 sacc[8] = {};
#pragma unroll
        for (int kt = 0; kt < 8; kt++) {
            short8 bk0 = *(const short8*)&Ks[kt * 16 + lane16][quad * 8];
            short8 bk1 = *(const short8*)&Ks[kt * 16 + lane16][32 + quad * 8];
            sacc[kt] = __builtin_amdgcn_mfma_f32_16x16x32_bf16(aq0, bk0, sacc[kt], 0, 0, 0);
            sacc[kt] = __builtin_amdgcn_mfma_f32_16x16x32_bf16(aq1, bk1, sacc[kt], 0, 0, 0);
        }

        // ---- static-max softmax: p = 2^(s*C1 - C2); mask only on last chunk ----
        bool domask = (kc + 2 > qb);   // wave-uniform
#pragma unroll
        for (int r = 0; r < 4; r++) {
            int qrow = q0 + wave * 16 + quad * 4 + r;
#pragma unroll
            for (int kt = 0; kt < 8; kt++) {
                float s = sacc[kt][r];
                if (domask) {
                    int key = kc * 64 + kt * 16 + lane16;
                    s = (key <= qrow) ? s : -__builtin_inff();
                }
                float p = exp2f(fmaf(s, C1, -C2));   // masked -> 0
                l_part[r] += p;
                Ps[wave][quad * 4 + r][kt * 16 + lane16] =
                    (unsigned short)(__float_as_uint(p) >> 16);   // truncated bf16
            }
        }
        // no barrier: Ps is wave-private; in-wave RAW ordered by lgkmcnt

        // ---- O += P V  (A=P rows, B=V^T rows, both key-contiguous) ----
#pragma unroll
        for (int s = 0; s < 4; s++) {
            short8 ap = *(const short8*)&Ps[wave][lane16][s * 32 + quad * 8];
#pragma unroll
            for (int dt = 0; dt < 4; dt++) {
                short8 bv = *(const short8*)&Vt[dt * 16 + lane16][s * 32 + quad * 8];
                Oacc[dt] = __builtin_amdgcn_mfma_f32_16x16x32_bf16(ap, bv, Oacc[dt], 0, 0, 0);
            }
        }
    }

    // deferred l reduction (sum over lane16 key-group) + output
    float invl[4];
#pragma unroll
    for (int r = 0; r < 4; r++) {
        float lf = l_part[r];
        lf += __shfl_xor(lf, 1);
        lf += __shfl_xor(lf, 2);
        lf += __shfl_xor(lf, 4);
        lf += __shfl_xor(lf, 8);
        invl[r] = 1.0f / lf;
    }
#pragma unroll
    for (int dt = 0; dt < 4; dt++) {
#pragma unroll
        for (int r = 0; r < 4; r++) {
            int qrow = q0 + wave * 16 + quad * 4 + r;
            out[(size_t)qrow * 1024 + h * 64 + dt * 16 + lane16] = f2b(Oacc[dt][r] * invl[r]);
        }
    }
}

// ---------- launch ----------
extern "C" void kernel_launch(void* const* d_in, const int* in_sizes, int n_in,
                              void* d_out, int out_size, void* d_ws, size_t ws_size,
                              hipStream_t stream) {
    const float* x      = (const float*)d_in[0];
    const float* w_qkv  = (const float*)d_in[1];
    const float* w_attn = (const float*)d_in[2];
    const float* w_fc   = (const float*)d_in[3];
    const float* w_mlp  = (const float*)d_in[4];
    const float* ln1w   = (const float*)d_in[5];
    const float* ln2w   = (const float*)d_in[6];

    char* ws = (char*)d_ws;   // total 112 MB, no aliasing
    unsigned short* h      = (unsigned short*)(ws + 0);          //  8 MB
    unsigned short* wqkvT  = (unsigned short*)(ws + 8388608);    //  6 MB
    unsigned short* wattnT = (unsigned short*)(ws + 14680064);   //  2 MB
    unsigned short* wfcT   = (unsigned short*)(ws + 16777216);   //  8 MB
    unsigned short* wmlpT  = (unsigned short*)(ws + 25165824);   //  8 MB
    unsigned short* qkv    = (unsigned short*)(ws + 33554432);   // 24 MB
    unsigned short* attno  = (unsigned short*)(ws + 58720256);   //  8 MB
    float*          x2     = (float*)(ws + 67108864);            // 16 MB
    unsigned short* fcact  = (unsigned short*)(ws + 83886080);   // 32 MB
    float* outF = (float*)d_out;

    k_transpose_all<<<12288, dim3(32, 8), 0, stream>>>(
        w_qkv, w_attn, w_fc, w_mlp, wqkvT, wattnT, wfcT, wmlpT);

    k_layernorm<<<4096, 256, 0, stream>>>(x, ln1w, h);
    k_gemm_bt<1, 128, 128, 3><<<dim3(24, 32), 256, 0, stream>>>(h, wqkvT, nullptr, qkv, 4096, 3072, 1024);
    k_attn<<<1024, 256, 0, stream>>>(qkv, attno);
    k_gemm_bt<2, 64, 64, 4><<<dim3(16, 64), 256, 0, stream>>>(attno, wattnT, x, x2, 4096, 1024, 1024);
    k_layernorm<<<4096, 256, 0, stream>>>(x2, ln2w, h);
    k_gemm_bt<3, 128, 128, 3><<<dim3(32, 32), 256, 0, stream>>>(h, wfcT, nullptr, fcact, 4096, 4096, 1024);
    k_gemm_bt<2, 64, 64, 4><<<dim3(16, 64), 256, 0, stream>>>(fcact, wmlpT, x2, outF, 4096, 1024, 4096);
}

// Round 13
// 354.923 us; speedup vs baseline: 2.1143x; 1.0288x over previous
//
#include <hip/hip_runtime.h>
#include <cstdint>

// ---------- helpers ----------
typedef __attribute__((ext_vector_type(8))) short short8;   // 8 x bf16 (4 VGPRs)
typedef __attribute__((ext_vector_type(4))) float f32x4;

__device__ __forceinline__ float b2f(unsigned short u) {
    return __uint_as_float(((unsigned int)u) << 16);
}
__device__ __forceinline__ unsigned short f2b(float f) {   // RNE f32->bf16
    unsigned int u = __float_as_uint(f);
    u += 0x7FFFu + ((u >> 16) & 1u);
    return (unsigned short)(u >> 16);
}

// ---------- fused transpose + fp32->bf16 convert for all 4 weights ----------
__global__ __launch_bounds__(256) void k_transpose_all(
        const float* __restrict__ w0, const float* __restrict__ w1,
        const float* __restrict__ w2, const float* __restrict__ w3,
        unsigned short* __restrict__ o0, unsigned short* __restrict__ o1,
        unsigned short* __restrict__ o2, unsigned short* __restrict__ o3) {
    __shared__ float tile[32][33];
    int b = blockIdx.x;
    const float* w; unsigned short* o; int K, N, nx, tb;
    if (b < 3072)      { w = w0; o = o0; K = 1024; N = 3072; nx = 96;  tb = b; }
    else if (b < 4096) { w = w1; o = o1; K = 1024; N = 1024; nx = 32;  tb = b - 3072; }
    else if (b < 8192) { w = w2; o = o2; K = 1024; N = 4096; nx = 128; tb = b - 4096; }
    else               { w = w3; o = o3; K = 4096; N = 1024; nx = 32;  tb = b - 8192; }
    int n0 = (tb % nx) * 32, k0 = (tb / nx) * 32;
    int tx = threadIdx.x, ty = threadIdx.y;
#pragma unroll
    for (int i = 0; i < 4; i++)
        tile[ty + 8 * i][tx] = w[(size_t)(k0 + ty + 8 * i) * N + n0 + tx];
    __syncthreads();
#pragma unroll
    for (int i = 0; i < 4; i++)
        o[(size_t)(n0 + ty + 8 * i) * K + k0 + tx] = f2b(tile[tx][ty + 8 * i]);
}

// ---------- layernorm (fp32 in, bf16 out), one row (C=1024) per block ----------
__global__ __launch_bounds__(256) void k_layernorm(
        const float* __restrict__ x, const float* __restrict__ w,
        unsigned short* __restrict__ out) {
    int row = blockIdx.x, tid = threadIdx.x;
    const float4* xr = (const float4*)(x + (size_t)row * 1024);
    float4 v = xr[tid];
    float s  = v.x + v.y + v.z + v.w;
    float ss = v.x * v.x + v.y * v.y + v.z * v.z + v.w * v.w;
#pragma unroll
    for (int off = 32; off >= 1; off >>= 1) {
        s  += __shfl_down(s, off);
        ss += __shfl_down(ss, off);
    }
    __shared__ float red[10];
    if ((tid & 63) == 0) { red[tid >> 6] = s; red[4 + (tid >> 6)] = ss; }
    __syncthreads();
    if (tid == 0) {
        float S  = red[0] + red[1] + red[2] + red[3];
        float SS = red[4] + red[5] + red[6] + red[7];
        float mu  = S * (1.0f / 1024.0f);
        float var = SS * (1.0f / 1024.0f) - mu * mu;
        red[8] = mu; red[9] = rsqrtf(var + 1e-5f);
    }
    __syncthreads();
    float mu = red[8], rs = red[9];
    float4 wv = ((const float4*)w)[tid];
    ushort4 pk;
    pk.x = f2b((v.x - mu) * rs * wv.x);
    pk.y = f2b((v.y - mu) * rs * wv.y);
    pk.z = f2b((v.z - mu) * rs * wv.z);
    pk.w = f2b((v.w - mu) * rs * wv.w);
    *(ushort4*)(out + (size_t)row * 1024 + tid * 4) = pk;
}

// ---------- split-K reduce: out = res + p0 + p1 (fp32, vectorized) ----------
__global__ __launch_bounds__(256) void k_reduce(
        const float* __restrict__ res, const float* __restrict__ p0,
        const float* __restrict__ p1, float* __restrict__ out, int n4) {
    int i = blockIdx.x * 256 + threadIdx.x;
    if (i < n4) {
        float4 a = ((const float4*)res)[i];
        float4 b = ((const float4*)p0)[i];
        float4 c = ((const float4*)p1)[i];
        a.x += b.x + c.x; a.y += b.y + c.y; a.z += b.z + c.z; a.w += b.w + c.w;
        ((float4*)out)[i] = a;
    }
}

// ---------- bf16 MFMA GEMM: C[M][N] = A[M][K] @ BT[N][K]^T (+ epilogue) ----------
// BK=64, column-rotate LDS swizzle (0 conflicts), named-scalar VGPR prefetch.
// TM=128/TN=128: 2x2 waves of 64x64. Split-K via gridDim.z (EPI=0 partials).
// EPI: 0 = f32 partial store (z-offset), 1 = bf16, 3 = gelu -> bf16
template <int EPI, int TM, int TN, int MINW>
__global__ __launch_bounds__(256, MINW) void k_gemm_bt(
        const unsigned short* __restrict__ A, const unsigned short* __restrict__ BT,
        const float* __restrict__ RES, void* __restrict__ OUT,
        int M, int N, int K) {
    constexpr int WT = (TM == 128) ? 64 : 32;      // wave tile (square)
    constexpr int MI = WT / 16;                    // subtiles per wave (each dim)
    constexpr int NA = TM / 32, NB = TN / 32;      // staging uint4-chunks per thread
    __shared__ __align__(16) unsigned short As[TM * 64];
    __shared__ __align__(16) unsigned short Bs[TN * 64];
    int tid  = threadIdx.x;
    int lane = tid & 63, wave = tid >> 6;
    int quad = lane >> 4, qr = lane & 15;
    int wm_off = (wave >> 1) * WT;
    int wn_off = (wave & 1) * WT;
    int m0 = blockIdx.y * TM, n0 = blockIdx.x * TN;
    int ks = K / gridDim.z;                         // split-K slice
    int kbeg = blockIdx.z * ks;
    int r0 = tid >> 3;                      // 0..31
    int c0 = (tid & 7) * 8;
    int cs = 8 * (((tid & 7) + (r0 & 7)) & 7);
    int cswz[2];
#pragma unroll
    for (int kk = 0; kk < 2; kk++) cswz[kk] = 8 * (((kk * 4) + quad + (qr & 7)) & 7);

    const unsigned short* Ap = A  + (size_t)(m0 + r0) * K + kbeg + c0;
    const unsigned short* Bp = BT + (size_t)(n0 + r0) * K + kbeg + c0;
    const size_t sA = (size_t)32 * K;

    uint4 pa0, pa1, pa2, pa3, pb0, pb1, pb2, pb3;
    pa0 = *(const uint4*)(Ap);
    pa1 = *(const uint4*)(Ap + sA);
    if constexpr (NA == 4) {
        pa2 = *(const uint4*)(Ap + 2 * sA);
        pa3 = *(const uint4*)(Ap + 3 * sA);
    }
    pb0 = *(const uint4*)(Bp);
    pb1 = *(const uint4*)(Bp + sA);
    if constexpr (NB == 4) {
        pb2 = *(const uint4*)(Bp + 2 * sA);
        pb3 = *(const uint4*)(Bp + 3 * sA);
    }

    f32x4 acc[MI][MI] = {};
    for (int k0 = 0; k0 < ks; k0 += 64) {
        __syncthreads();   // prev compute's LDS reads done
        *(uint4*)&As[(r0)      * 64 + cs] = pa0;
        *(uint4*)&As[(32 + r0) * 64 + cs] = pa1;
        if constexpr (NA == 4) {
            *(uint4*)&As[(64 + r0) * 64 + cs] = pa2;
            *(uint4*)&As[(96 + r0) * 64 + cs] = pa3;
        }
        *(uint4*)&Bs[(r0)      * 64 + cs] = pb0;
        *(uint4*)&Bs[(32 + r0) * 64 + cs] = pb1;
        if constexpr (NB == 4) {
            *(uint4*)&Bs[(64 + r0) * 64 + cs] = pb2;
            *(uint4*)&Bs[(96 + r0) * 64 + cs] = pb3;
        }
        __syncthreads();
        if (k0 + 64 < ks) {   // prefetch next slab; vmcnt waits land next iteration
            int k = k0 + 64;
            pa0 = *(const uint4*)(Ap + k);
            pa1 = *(const uint4*)(Ap + sA + k);
            if constexpr (NA == 4) {
                pa2 = *(const uint4*)(Ap + 2 * sA + k);
                pa3 = *(const uint4*)(Ap + 3 * sA + k);
            }
            pb0 = *(const uint4*)(Bp + k);
            pb1 = *(const uint4*)(Bp + sA + k);
            if constexpr (NB == 4) {
                pb2 = *(const uint4*)(Bp + 2 * sA + k);
                pb3 = *(const uint4*)(Bp + 3 * sA + k);
            }
        }
#pragma unroll
        for (int kk = 0; kk < 2; kk++) {
            short8 af[MI], bfr[MI];
#pragma unroll
            for (int i = 0; i < MI; i++) af[i]  = *(const short8*)&As[(wm_off + i * 16 + qr) * 64 + cswz[kk]];
#pragma unroll
            for (int j = 0; j < MI; j++) bfr[j] = *(const short8*)&Bs[(wn_off + j * 16 + qr) * 64 + cswz[kk]];
#pragma unroll
            for (int i = 0; i < MI; i++)
#pragma unroll
                for (int j = 0; j < MI; j++)
                    acc[i][j] = __builtin_amdgcn_mfma_f32_16x16x32_bf16(af[i], bfr[j], acc[i][j], 0, 0, 0);
        }
    }
    // epilogue: C/D layout col=lane&15, row=quad*4+reg
    float* outz = (EPI == 0) ? ((float*)OUT + (size_t)blockIdx.z * M * N) : (float*)OUT;
#pragma unroll
    for (int i = 0; i < MI; i++) {
#pragma unroll
        for (int j = 0; j < MI; j++) {
#pragma unroll
            for (int r = 0; r < 4; r++) {
                int row = m0 + wm_off + i * 16 + quad * 4 + r;
                int col = n0 + wn_off + j * 16 + qr;
                size_t idx = (size_t)row * N + col;
                float v = acc[i][j][r];
                if (EPI == 0)      outz[idx] = v;
                else if (EPI == 1) ((unsigned short*)OUT)[idx] = f2b(v);
                else if (EPI == 2) ((float*)OUT)[idx] = RES[idx] + v;
                else {
                    // tanh-form GELU via exp2: g = v*t/(t+1), t = 2^(2u/ln2)
                    float u = v * fmaf(v * v, 0.035677408f, 0.79788456f);
                    float e = fminf(u * 2.885390082f, 80.0f);   // guard inf/inf
                    float t = exp2f(e);
                    float g = v * t / (t + 1.0f);
                    ((unsigned short*)OUT)[idx] = f2b(g);
                }
            }
        }
    }
}

// ---------- MFMA causal flash attention, K-chunk=128, static-max softmax ------
// Register-prefetch pipeline; Ps via truncated bf16. (byte-identical to R12)
__global__ __launch_bounds__(256) void k_attn(
        const unsigned short* __restrict__ qkv, unsigned short* __restrict__ out) {
    __shared__ unsigned short Ks[128][72];      // K rows (Q staged here first)
    __shared__ unsigned short Vt[64][136];      // [dim][key 0..127]
    __shared__ unsigned short Ps[4][16][136];   // per wave [q][key 0..127] (wave-private)

    const float C1 = 0.18033688f;   // 0.125 * log2(e)
    const float C2 = 5.77078016f;   // 4.0   * log2(e)  (static max m=4)

    int l = blockIdx.x;                // 0..1023; big qb dispatched first
    int h = l & 15;
    int qb = 63 - (l >> 4);
    int q0 = qb * 64;

    int tid = threadIdx.x;
    int wave = tid >> 6, lane = tid & 63;
    int lane16 = lane & 15, quad = lane >> 4;

    // ---- stage Q through Ks rows 0..63, read loop-invariant A-frags ----
    {
        int srow = tid >> 2, sc0 = (tid & 3) * 16;
        size_t base = (size_t)(q0 + srow) * 3072 + h * 64 + sc0;
        *(uint4*)&Ks[srow][sc0]     = *(const uint4*)&qkv[base];
        *(uint4*)&Ks[srow][sc0 + 8] = *(const uint4*)&qkv[base + 8];
    }
    __syncthreads();
    short8 aq0 = *(const short8*)&Ks[wave * 16 + lane16][quad * 8];
    short8 aq1 = *(const short8*)&Ks[wave * 16 + lane16][32 + quad * 8];

    f32x4 Oacc[4] = {};                // lane holds O[q=quad*4+r][d=dt*16+lane16]
    float l_part[4] = {0.f, 0.f, 0.f, 0.f};

    int srow = tid >> 1, sc0 = (tid & 1) * 32;   // K staging coords
    int vk = (lane & 31) * 2;                    // V staging: even local key
    int d0 = wave * 16 + (lane >> 5) * 8;

    // prefetch registers (chunk kc): K 4x uint4, V 4x uint4
    uint4 pk0, pk1, pk2, pk3, pv0, pv1, pv2, pv3;
    {   // prefetch chunk 0
        size_t base = (size_t)srow * 3072 + 1024 + h * 64 + sc0;
        pk0 = *(const uint4*)&qkv[base];
        pk1 = *(const uint4*)&qkv[base + 8];
        pk2 = *(const uint4*)&qkv[base + 16];
        pk3 = *(const uint4*)&qkv[base + 24];
        size_t vb0 = (size_t)vk * 3072 + 2048 + h * 64 + d0;
        pv0 = *(const uint4*)&qkv[vb0];
        pv1 = *(const uint4*)&qkv[vb0 + 3072];
        size_t vb1 = (size_t)(64 + vk) * 3072 + 2048 + h * 64 + d0;
        pv2 = *(const uint4*)&qkv[vb1];
        pv3 = *(const uint4*)&qkv[vb1 + 3072];
    }

    for (int kc = 0; kc <= qb; kc += 2) {      // 128 keys per iteration
        __syncthreads();   // prev-iter LDS reads done (covers Q-frag reads at kc=0)
        {   // write prefetched K chunk to LDS
            *(uint4*)&Ks[srow][sc0]      = pk0;
            *(uint4*)&Ks[srow][sc0 + 8]  = pk1;
            *(uint4*)&Ks[srow][sc0 + 16] = pk2;
            *(uint4*)&Ks[srow][sc0 + 24] = pk3;
        }
        {   // write prefetched V chunk TRANSPOSED, key-pairs packed as b32
            const unsigned short* pe0 = (const unsigned short*)&pv0;
            const unsigned short* po0 = (const unsigned short*)&pv1;
            const unsigned short* pe1 = (const unsigned short*)&pv2;
            const unsigned short* po1 = (const unsigned short*)&pv3;
#pragma unroll
            for (int j = 0; j < 8; j++) {
                *(uint32_t*)&Vt[d0 + j][vk]      = (uint32_t)pe0[j] | ((uint32_t)po0[j] << 16);
                *(uint32_t*)&Vt[d0 + j][64 + vk] = (uint32_t)pe1[j] | ((uint32_t)po1[j] << 16);
            }
        }
        __syncthreads();

        if (kc + 2 <= qb) {   // issue next chunk's loads; overlap with compute below
            size_t base = (size_t)((kc + 2) * 64 + srow) * 3072 + 1024 + h * 64 + sc0;
            pk0 = *(const uint4*)&qkv[base];
            pk1 = *(const uint4*)&qkv[base + 8];
            pk2 = *(const uint4*)&qkv[base + 16];
            pk3 = *(const uint4*)&qkv[base + 24];
            size_t vb0 = (size_t)((kc + 2) * 64 + vk) * 3072 + 2048 + h * 64 + d0;
            pv0 = *(const uint4*)&qkv[vb0];
            pv1 = *(const uint4*)&qkv[vb0 + 3072];
            size_t vb1 = (size_t)((kc + 3) * 64 + vk) * 3072 + 2048 + h * 64 + d0;
            pv2 = *(const uint4*)&qkv[vb1];
            pv3 = *(const uint4*)&qkv[vb1 + 3072];
        }

        // ---- S = Q K^T  (16q x 128k per wave) ----
        f32x4 sacc[8] = {};
#pragma unroll
        for (int kt = 0; kt < 8; kt++) {
            short8 bk0 = *(const short8*)&Ks[kt * 16 + lane16][quad * 8];
            short8 bk1 = *(const short8*)&Ks[kt * 16 + lane16][32 + quad * 8];
            sacc[kt] = __builtin_amdgcn_mfma_f32_16x16x32_bf16(aq0, bk0, sacc[kt], 0, 0, 0);
            sacc[kt] = __builtin_amdgcn_mfma_f32_16x16x32_bf16(aq1, bk1, sacc[kt], 0, 0, 0);
        }

        // ---- static-max softmax: p = 2^(s*C1 - C2); mask only on last chunk ----
        bool domask = (kc + 2 > qb);   // wave-uniform
#pragma unroll
        for (int r = 0; r < 4; r++) {
            int qrow = q0 + wave * 16 + quad * 4 + r;
#pragma unroll
            for (int kt = 0; kt < 8; kt++) {
                float s = sacc[kt][r];
                if (domask) {
                    int key = kc * 64 + kt * 16 + lane16;
                    s = (key <= qrow) ? s : -__builtin_inff();
                }
                float p = exp2f(fmaf(s, C1, -C2));   // masked -> 0
                l_part[r] += p;
                Ps[wave][quad * 4 + r][kt * 16 + lane16] =
                    (unsigned short)(__float_as_uint(p) >> 16);   // truncated bf16
            }
        }
        // no barrier: Ps is wave-private; in-wave RAW ordered by lgkmcnt

        // ---- O += P V  (A=P rows, B=V^T rows, both key-contiguous) ----
#pragma unroll
        for (int s = 0; s < 4; s++) {
            short8 ap = *(const short8*)&Ps[wave][lane16][s * 32 + quad * 8];
#pragma unroll
            for (int dt = 0; dt < 4; dt++) {
                short8 bv = *(const short8*)&Vt[dt * 16 + lane16][s * 32 + quad * 8];
                Oacc[dt] = __builtin_amdgcn_mfma_f32_16x16x32_bf16(ap, bv, Oacc[dt], 0, 0, 0);
            }
        }
    }

    // deferred l reduction (sum over lane16 key-group) + output
    float invl[4];
#pragma unroll
    for (int r = 0; r < 4; r++) {
        float lf = l_part[r];
        lf += __shfl_xor(lf, 1);
        lf += __shfl_xor(lf, 2);
        lf += __shfl_xor(lf, 4);
        lf += __shfl_xor(lf, 8);
        invl[r] = 1.0f / lf;
    }
#pragma unroll
    for (int dt = 0; dt < 4; dt++) {
#pragma unroll
        for (int r = 0; r < 4; r++) {
            int qrow = q0 + wave * 16 + quad * 4 + r;
            out[(size_t)qrow * 1024 + h * 64 + dt * 16 + lane16] = f2b(Oacc[dt][r] * invl[r]);
        }
    }
}

// ---------- launch ----------
extern "C" void kernel_launch(void* const* d_in, const int* in_sizes, int n_in,
                              void* d_out, int out_size, void* d_ws, size_t ws_size,
                              hipStream_t stream) {
    const float* x      = (const float*)d_in[0];
    const float* w_qkv  = (const float*)d_in[1];
    const float* w_attn = (const float*)d_in[2];
    const float* w_fc   = (const float*)d_in[3];
    const float* w_mlp  = (const float*)d_in[4];
    const float* ln1w   = (const float*)d_in[5];
    const float* ln2w   = (const float*)d_in[6];

    char* ws = (char*)d_ws;   // total 116 MB (region reuse for split-K partials)
    unsigned short* h      = (unsigned short*)(ws + 0);          //  8 MB
    unsigned short* wqkvT  = (unsigned short*)(ws + 8388608);    //  6 MB
    unsigned short* wattnT = (unsigned short*)(ws + 14680064);   //  2 MB
    unsigned short* wfcT   = (unsigned short*)(ws + 16777216);   //  8 MB
    unsigned short* wmlpT  = (unsigned short*)(ws + 25165824);   //  8 MB
    unsigned short* qkv    = (unsigned short*)(ws + 33554432);   // 24 MB
    unsigned short* attno  = (unsigned short*)(ws + 58720256);   //  8 MB
    float*          x2     = (float*)(ws + 67108864);            // 16 MB
    unsigned short* fcact  = (unsigned short*)(ws + 83886080);   // 32 MB
    // split-K partials (32 MB each, region-reuse of dead buffers):
    float* pA = (float*)(ws + 83886080);   // attn_proj partials: fcact region (dead until fc)
    float* pM = (float*)(ws + 33554432);   // mlp partials: qkv+attno region (dead after attn_proj)
    float* outF = (float*)d_out;

    k_transpose_all<<<12288, dim3(32, 8), 0, stream>>>(
        w_qkv, w_attn, w_fc, w_mlp, wqkvT, wattnT, wfcT, wmlpT);

    k_layernorm<<<4096, 256, 0, stream>>>(x, ln1w, h);
    k_gemm_bt<1, 128, 128, 3><<<dim3(24, 32), 256, 0, stream>>>(h, wqkvT, nullptr, qkv, 4096, 3072, 1024);
    k_attn<<<1024, 256, 0, stream>>>(qkv, attno);
    // attn_proj: split-K=2, fp32 partials -> pA; reduce adds residual x
    k_gemm_bt<0, 128, 128, 3><<<dim3(8, 32, 2), 256, 0, stream>>>(attno, wattnT, nullptr, pA, 4096, 1024, 1024);
    k_reduce<<<4096, 256, 0, stream>>>(x, pA, pA + 4194304, x2, 1048576);
    k_layernorm<<<4096, 256, 0, stream>>>(x2, ln2w, h);
    k_gemm_bt<3, 128, 128, 3><<<dim3(32, 32), 256, 0, stream>>>(h, wfcT, nullptr, fcact, 4096, 4096, 1024);
    // mlp_proj: split-K=2, fp32 partials -> pM; reduce adds residual x2
    k_gemm_bt<0, 128, 128, 3><<<dim3(8, 32, 2), 256, 0, stream>>>(fcact, wmlpT, nullptr, pM, 4096, 1024, 4096);
    k_reduce<<<4096, 256, 0, stream>>>(x2, pM, pM + 4194304, outF, 1048576);
}